// Round 13
// baseline (343.435 us; speedup 1.0000x reference)
//
#include <hip/hip_runtime.h>
#include <hip/hip_bf16.h>

// ---------------- problem constants ----------------
#define B_    4
#define L_    2048
#define DM    672
#define DI    1344
#define DS    128
#define NH    24
#define HD    56
#define CH    32
#define NC    64
#define DIP   2968
#define CD    1600
#define NTOK  (B_*L_)

typedef __attribute__((ext_vector_type(8))) short short8;
typedef __attribute__((ext_vector_type(4))) float f32x4;
typedef __attribute__((ext_vector_type(4))) unsigned int u32x4;
typedef __hip_bfloat16 bf16;

// ---------------- workspace layout (bytes) ----------------
static constexpr size_t OFF_W1   = 0;            // bf16 [2968][672]
static constexpr size_t OFF_W2   = 3989504;      // bf16 [672][1344]
static constexpr size_t OFF_XB   = 5795840;      // bf16 [8192][672]
static constexpr size_t OFF_ZX   = 16805888;     // bf16 [8192][2968] (48.6MB)
static constexpr size_t OFF_DTRAW= 65433600;     // f32  [8192][24] raw dt accums
static constexpr size_t OFF_XIN  = 114061312;    // bf16 [8192][1344]
static constexpr size_t OFF_BM   = 136081408;    // bf16 [8192][128]
static constexpr size_t OFF_CM   = 138178560;    // bf16 [8192][128]
static constexpr size_t OFF_DTT  = 140275712;    // f32  [B][NH][L]
static constexpr size_t OFF_CDEC = 141062144;    // f32  [B][NH][NC]
static constexpr size_t OFF_G    = 141086720;    // f32  [B*NC][1024]
static constexpr size_t OFF_Y    = 142135296;    // bf16 [8192][1344]
static constexpr size_t OFF_Y2   = 164155392;    // bf16 [8192][1344]
static constexpr size_t OFF_ST   = 186175488;    // bf16 states: 44MB (2-pass) or 88MB (1-pass)
static constexpr size_t ST_ONEPASS_END = OFF_ST + (size_t)B_ * NH * NC * HD * DS * 2; // 274MB

__device__ __forceinline__ void gload16(const bf16* g, bf16* l) {
    __builtin_amdgcn_global_load_lds(
        (const __attribute__((address_space(1))) unsigned int*)g,
        (__attribute__((address_space(3))) unsigned int*)l, 16, 0, 0);
}
__device__ __forceinline__ float bf2f(short s) {
    unsigned int u = ((unsigned int)(unsigned short)s) << 16;
    return __builtin_bit_cast(float, u);
}
__device__ __forceinline__ short f2bf(float f) {
    bf16 h = __float2bfloat16(f);
    return *reinterpret_cast<short*>(&h);
}
__device__ __forceinline__ unsigned int pack2(float a, float b) {
    return (unsigned int)(unsigned short)f2bf(a)
         | ((unsigned int)(unsigned short)f2bf(b) << 16);
}

// ---------------- weight cast ----------------
__global__ __launch_bounds__(256) void cast_weights(
    const float* __restrict__ w1, const float* __restrict__ w2,
    bf16* __restrict__ w1b, bf16* __restrict__ w2b)
{
    int i = blockIdx.x * 256 + threadIdx.x;
    const int W1N = DIP * DM;
    const int W2N = DM * DI;
    if (i < W1N) w1b[i] = __float2bfloat16(w1[i]);
    int j = i - W1N;
    if (j >= 0 && j < W2N) w2b[j] = __float2bfloat16(w2[j]);
}

// ---------------- input RMSNorm + cast to bf16 ----------------
__global__ __launch_bounds__(256) void rmsnorm_kernel(
    const float* __restrict__ in, const float* __restrict__ w,
    bf16* __restrict__ out)
{
    const int tok = blockIdx.x;
    const int tid = threadIdx.x;
    __shared__ float red[4];
    float v[3];
    float ss = 0.f;
    int idx = tid;
#pragma unroll
    for (int j = 0; j < 3; ++j) {
        float x = 0.f;
        if (idx < DM) x = in[(size_t)tok * DM + idx];
        v[j] = x; ss += x * x;
        idx += 256;
    }
    for (int o = 32; o > 0; o >>= 1) ss += __shfl_down(ss, o, 64);
    if ((tid & 63) == 0) red[tid >> 6] = ss;
    __syncthreads();
    float tot = red[0] + red[1] + red[2] + red[3];
    float r = rsqrtf(tot / (float)DM + 1e-5f);
    idx = tid;
#pragma unroll
    for (int j = 0; j < 3; ++j) {
        if (idx < DM) out[(size_t)tok * DM + idx] = __float2bfloat16(v[j] * r * w[idx]);
        idx += 256;
    }
}

// ---------------- GEMM1: 256x128 tile, 8 waves, dbuf gload-lds, bf16 epilogue ------
// Per-wave structure identical to R12 (acc[4][4], same frag reads, same epilogue,
// same dtraw cold branch at blockIdx.y==23); wave grid 4(row-quarters) x 2(col-halves).
// Per-CU: 3 blk x 8 waves, 16 MFMA / 3 gload16 per wave per K-step (+33% vs R12).
__global__ __launch_bounds__(512) void gemm1_bf16(
    const bf16* __restrict__ A, const bf16* __restrict__ W,
    bf16* __restrict__ Co, float* __restrict__ dtraw,
    int M, int N, int K)
{
    __shared__ bf16 As[2 * 256 * 32];   // buffer stride 8192 elems
    __shared__ bf16 Bs[2 * 128 * 32];   // buffer stride 4096 elems
    const int tid = threadIdx.x, lane = tid & 63, w = tid >> 6;  // w 0..7
    const int wq = w >> 1, wn = w & 1;
    const int m0 = blockIdx.x * 256, n0 = blockIdx.y * 128;
    const int lr = lane & 15, kg = lane >> 4;
    f32x4 acc[4][4] = {};

    // staging: wave w owns A rows [w*32, w*32+32) (2 instrs), B rows [w*16, w*16+16) (1)
    const int srA = w * 32 + (lane >> 2);
    const int srB = w * 16 + (lane >> 2);
    const int sc = (lane & 3) * 8;
    const bf16* ga0 = A + (size_t)(m0 + srA) * K + sc;
    const bf16* ga1 = ga0 + (size_t)16 * K;
    int nrB = n0 + srB; if (nrB >= N) nrB = N - 1;
    const bf16* gb0 = W + (size_t)nrB * K + sc;
    bf16* la = &As[w * 1024];
    bf16* lb = &Bs[w * 512];

    const int nK = K >> 5;
    gload16(ga0, la); gload16(ga1, la + 512); gload16(gb0, lb);
    ga0 += 32; ga1 += 32; gb0 += 32;

    int cur = 0;
    for (int kt = 0; kt < nK; ++kt) {
        __syncthreads();
        if (kt + 1 < nK) {
            const int nbA = (cur ^ 1) * 8192, nbB = (cur ^ 1) * 4096;
            gload16(ga0, la + nbA); gload16(ga1, la + nbA + 512);
            gload16(gb0, lb + nbB);
            ga0 += 32; ga1 += 32; gb0 += 32;
        }
        const bf16* Ab = &As[cur * 8192];
        const bf16* Bb = &Bs[cur * 4096];
        short8 af[4], bfr[4];
#pragma unroll
        for (int i = 0; i < 4; ++i) {
            af[i]  = *reinterpret_cast<const short8*>(&Ab[(wq * 64 + i * 16 + lr) * 32 + kg * 8]);
            bfr[i] = *reinterpret_cast<const short8*>(&Bb[(wn * 64 + i * 16 + lr) * 32 + kg * 8]);
        }
#pragma unroll
        for (int i = 0; i < 4; ++i)
#pragma unroll
            for (int j = 0; j < 4; ++j)
                acc[i][j] = __builtin_amdgcn_mfma_f32_16x16x32_bf16(af[i], bfr[j], acc[i][j], 0, 0, 0);
        cur ^= 1;
    }
    // pure bf16 epilogue
#pragma unroll
    for (int i = 0; i < 4; ++i) {
        int row = m0 + wq * 64 + i * 16 + kg * 4;
#pragma unroll
        for (int j = 0; j < 4; ++j) {
            int col = n0 + wn * 64 + j * 16 + lr;
            if (col < N) {
#pragma unroll
                for (int r = 0; r < 4; ++r)
                    Co[(size_t)(row + r) * N + col] = __float2bfloat16(acc[i][j][r]);
            }
        }
    }
    // cold, block-uniform: raw f32 dt accums for cols [DI+CD, DI+CD+NH)
    if (blockIdx.y == (DI + CD) / 128) {
#pragma unroll
        for (int i = 0; i < 4; ++i) {
            int row = m0 + wq * 64 + i * 16 + kg * 4;
#pragma unroll
            for (int j = 0; j < 4; ++j) {
                int d = wn * 64 + j * 16 + lr;   // n0 == DI+CD exactly
                if (d < NH) {
#pragma unroll
                    for (int r = 0; r < 4; ++r)
                        dtraw[(size_t)(row + r) * NH + d] = acc[i][j][r];
                }
            }
        }
    }
}

// ---------------- GEMM2: 128x64 tile, 2 waves, f32+resid out (R11-proven) ----------
__global__ __launch_bounds__(128) void gemm2_bt(
    const bf16* __restrict__ A, const bf16* __restrict__ W,
    const float* __restrict__ resid, float* __restrict__ Co,
    int M, int N, int K)
{
    __shared__ bf16 As[2 * 128 * 32];
    __shared__ bf16 Bs[2 * 64 * 32];
    const int tid = threadIdx.x, lane = tid & 63, w = tid >> 6;
    const int m0 = blockIdx.x * 128, n0 = blockIdx.y * 64;
    const int lr = lane & 15, kg = lane >> 4;
    f32x4 acc[4][4] = {};

    const int sr = lane >> 2;
    const int sc = (lane & 3) * 8;
    const bf16* ga[4];
#pragma unroll
    for (int i = 0; i < 4; ++i)
        ga[i] = A + (size_t)(m0 + w * 64 + i * 16 + sr) * K + sc;
    const bf16* gb[2];
#pragma unroll
    for (int j = 0; j < 2; ++j) {
        int nr = n0 + w * 32 + j * 16 + sr;
        if (nr >= N) nr = N - 1;
        gb[j] = W + (size_t)nr * K + sc;
    }
    bf16* laB = &As[w * 2048];
    bf16* lbB = &Bs[w * 1024];

    const int nK = K >> 5;
#pragma unroll
    for (int i = 0; i < 4; ++i) gload16(ga[i], laB + i * 512);
#pragma unroll
    for (int j = 0; j < 2; ++j) gload16(gb[j], lbB + j * 512);
#pragma unroll
    for (int i = 0; i < 4; ++i) ga[i] += 32;
#pragma unroll
    for (int j = 0; j < 2; ++j) gb[j] += 32;

    int cur = 0;
    for (int kt = 0; kt < nK; ++kt) {
        __syncthreads();
        if (kt + 1 < nK) {
            const int nbA = (cur ^ 1) * 4096, nbB = (cur ^ 1) * 2048;
#pragma unroll
            for (int i = 0; i < 4; ++i) gload16(ga[i], laB + nbA + i * 512);
#pragma unroll
            for (int j = 0; j < 2; ++j) gload16(gb[j], lbB + nbB + j * 512);
#pragma unroll
            for (int i = 0; i < 4; ++i) ga[i] += 32;
#pragma unroll
            for (int j = 0; j < 2; ++j) gb[j] += 32;
        }
        const bf16* Ab = &As[cur * 4096];
        const bf16* Bb = &Bs[cur * 2048];
        short8 af[4], bfr[4];
#pragma unroll
        for (int i = 0; i < 4; ++i)
            af[i] = *reinterpret_cast<const short8*>(&Ab[(w * 64 + i * 16 + lr) * 32 + kg * 8]);
#pragma unroll
        for (int j = 0; j < 4; ++j)
            bfr[j] = *reinterpret_cast<const short8*>(&Bb[(j * 16 + lr) * 32 + kg * 8]);
#pragma unroll
        for (int i = 0; i < 4; ++i)
#pragma unroll
            for (int j = 0; j < 4; ++j)
                acc[i][j] = __builtin_amdgcn_mfma_f32_16x16x32_bf16(af[i], bfr[j], acc[i][j], 0, 0, 0);
        cur ^= 1;
    }
#pragma unroll
    for (int i = 0; i < 4; ++i) {
        int row = m0 + w * 64 + i * 16 + kg * 4;
#pragma unroll
        for (int j = 0; j < 4; ++j) {
            int col = n0 + j * 16 + lr;
            if (col < N) {
#pragma unroll
                for (int r = 0; r < 4; ++r) {
                    size_t o = (size_t)(row + r) * N + col;
                    Co[o] = acc[i][j][r] + resid[o];
                }
            }
        }
    }
}

// ---------------- conv1d(4, causal, depthwise) + SiLU (bf16 in, x8) + dt ---------
__global__ __launch_bounds__(256) void conv_kernel(
    const bf16* __restrict__ zxb, const float* __restrict__ cw,
    const float* __restrict__ cb, const float* __restrict__ dtraw,
    const float* __restrict__ dtb,
    bf16* __restrict__ xin, bf16* __restrict__ Bm, bf16* __restrict__ Cm,
    float* __restrict__ dtT)      // [B][NH][L]
{
    const int tok = blockIdx.x;
    const int l = tok & (L_ - 1);
    const int tid = threadIdx.x;
    if (tid < 200) {
        const int ch0 = tid * 8;
        float xv[4][8];
#pragma unroll
        for (int k = 0; k < 4; ++k) {
            int li = l - 3 + k;
            if (li >= 0) {
                short8 v = *reinterpret_cast<const short8*>(
                    zxb + (size_t)(tok - 3 + k) * DIP + DI + ch0);
#pragma unroll
                for (int j = 0; j < 8; ++j) xv[k][j] = bf2f(v[j]);
            } else {
#pragma unroll
                for (int j = 0; j < 8; ++j) xv[k][j] = 0.f;
            }
        }
        const f32x4* cw4 = reinterpret_cast<const f32x4*>(cw + ch0 * 4);
        short8 o;
#pragma unroll
        for (int j = 0; j < 8; ++j) {
            f32x4 wv = cw4[j];
            float acc = cb[ch0 + j];
#pragma unroll
            for (int k = 0; k < 4; ++k) acc += xv[k][j] * wv[k];
            acc = acc / (1.f + expf(-acc));
            o[j] = f2bf(acc);
        }
        if (ch0 < DI)
            *reinterpret_cast<short8*>(xin + (size_t)tok * DI + ch0) = o;
        else if (ch0 < DI + DS)
            *reinterpret_cast<short8*>(Bm + (size_t)tok * DS + (ch0 - DI)) = o;
        else
            *reinterpret_cast<short8*>(Cm + (size_t)tok * DS + (ch0 - DI - DS)) = o;
    } else if (tid < 200 + NH) {
        const int hh = tid - 200;
        float v = dtraw[(size_t)tok * NH + hh] + dtb[hh];
        float sp = (v > 20.f) ? v : log1pf(expf(v));
        dtT[((size_t)((tok >> 11) * NH + hh)) * L_ + l] = sp;
    }
}

// ---------------- G = C.B^T per (b,chunk) via MFMA ----------------
__global__ __launch_bounds__(256) void g_mfma(
    const bf16* __restrict__ Bm, const bf16* __restrict__ Cm,
    float* __restrict__ Gp)
{
    const int bc = blockIdx.x;
    const int tok0 = (bc >> 6) * L_ + (bc & 63) * CH;
    const int tid = threadIdx.x, lane = tid & 63, w = tid >> 6;
    __shared__ bf16 Csh[32 * 136], Bsh[32 * 136];
    for (int i = tid; i < 4096; i += 256) {
        int l = i >> 7, n = i & 127;
        Csh[l * 136 + n] = Cm[(size_t)(tok0 + l) * DS + n];
        Bsh[l * 136 + n] = Bm[(size_t)(tok0 + l) * DS + n];
    }
    __syncthreads();
    const int mt = w >> 1, nt = w & 1;
    const int lr = lane & 15, kg = lane >> 4;
    f32x4 acc = {};
#pragma unroll
    for (int kt = 0; kt < 4; ++kt) {
        short8 a = *reinterpret_cast<const short8*>(&Csh[(mt * 16 + lr) * 136 + kt * 32 + kg * 8]);
        short8 b = *reinterpret_cast<const short8*>(&Bsh[(nt * 16 + lr) * 136 + kt * 32 + kg * 8]);
        acc = __builtin_amdgcn_mfma_f32_16x16x32_bf16(a, b, acc, 0, 0, 0);
    }
#pragma unroll
    for (int r = 0; r < 4; ++r) {
        int l = mt * 16 + kg * 4 + r, s = nt * 16 + lr;
        Gp[((size_t)bc << 10) + l * 32 + s] = acc[r];
    }
}

// ---------------- SSD phase B: per-chunk states via MFMA ----------------
__global__ __launch_bounds__(256) void ssd_states(
    const bf16* __restrict__ xin, const bf16* __restrict__ Bm,
    const float* __restrict__ dtT, const float* __restrict__ A_log,
    bf16* __restrict__ st, float* __restrict__ cdec, int nhp, int hs)
{
    const int blk = blockIdx.x;          // bh*NC + c
    const int c = blk & 63, bh = blk >> 6;
    const int hh = bh % nhp, b = bh / nhp;
    const int h = hs * nhp + hh;
    const int tok0 = b * L_ + c * CH;
    const int tid = threadIdx.x, lane = tid & 63, w = tid >> 6;
    const float Ah = -expf(A_log[h]);

    __shared__ bf16 xwT[64 * 40];
    __shared__ bf16 BmT[128 * 40];
    __shared__ float dts[32], acum[32], wdec[32];

    if (tid < 32) dts[tid] = dtT[((size_t)(b * NH + h)) * L_ + c * CH + tid];
    __syncthreads();
    if (tid < 32) { float s = 0.f; for (int i = 0; i <= tid; ++i) s += dts[i]; acum[tid] = s * Ah; }
    __syncthreads();
    if (tid < 32) wdec[tid] = expf(acum[31] - acum[tid]) * dts[tid];
    if (tid == 0) cdec[(size_t)(b * NH + h) * NC + c] = expf(acum[31]);
    for (int i = tid; i < 4096; i += 256) {
        int l = i >> 7, n = i & 127;
        BmT[n * 40 + l] = Bm[(size_t)(tok0 + l) * DS + n];
    }
    __syncthreads();
    for (int i = tid; i < 2048; i += 256) {
        int l = i >> 6, p = i & 63;
        float v = 0.f;
        if (p < HD) v = __bfloat162float(xin[(size_t)(tok0 + l) * DI + h * HD + p]) * wdec[l];
        xwT[p * 40 + l] = __float2bfloat16(v);
    }
    __syncthreads();

    const int lr = lane & 15, kg = lane >> 4;
    const int nt0 = w * 2;
    f32x4 acc[4][2] = {};
    short8 af[4], bfr[2];
#pragma unroll
    for (int mt = 0; mt < 4; ++mt)
        af[mt] = *reinterpret_cast<const short8*>(&xwT[(mt * 16 + lr) * 40 + kg * 8]);
#pragma unroll
    for (int j = 0; j < 2; ++j)
        bfr[j] = *reinterpret_cast<const short8*>(&BmT[((nt0 + j) * 16 + lr) * 40 + kg * 8]);
#pragma unroll
    for (int mt = 0; mt < 4; ++mt)
#pragma unroll
        for (int j = 0; j < 2; ++j)
            acc[mt][j] = __builtin_amdgcn_mfma_f32_16x16x32_bf16(af[mt], bfr[j], acc[mt][j], 0, 0, 0);

    bf16* sb = st + (size_t)blk * (HD * DS);
#pragma unroll
    for (int mt = 0; mt < 4; ++mt)
#pragma unroll
        for (int j = 0; j < 2; ++j) {
            int n = (nt0 + j) * 16 + lr;
#pragma unroll
            for (int r = 0; r < 4; ++r) {
                int p = mt * 16 + kg * 4 + r;
                if (p < HD) sb[p * DS + n] = __float2bfloat16(acc[mt][j][r]);
            }
        }
}

// ---------------- SSD phase C: in-place scan, 16B/lane (8 bf16) ----------------
__global__ __launch_bounds__(128) void ssd_scan(
    bf16* __restrict__ st, const float* __restrict__ cdec, int nhp, int hs)
{
    const int blk = blockIdx.x;   // bh*7 + sl
    const int sl = blk % 7;
    const int bh = blk / 7;
    const int b = bh / nhp, hh = bh % nhp;
    const int h = hs * nhp + hh;
    const int e = sl * 1024 + threadIdx.x * 8;   // 7*1024 = 7168 = HD*DS
    bf16* base = st + (size_t)bh * NC * (HD * DS) + e;
    const float* cd = cdec + (size_t)(b * NH + h) * NC;
    float c0 = 0.f, c1 = 0.f, c2 = 0.f, c3 = 0.f, c4 = 0.f, c5 = 0.f, c6 = 0.f, c7 = 0.f;
    for (int c = 0; c < NC; ++c) {
        u32x4* p = reinterpret_cast<u32x4*>(base + (size_t)c * (HD * DS));
        u32x4 sv = *p;
        float s0 = __builtin_bit_cast(float, sv[0] << 16);
        float s1 = __builtin_bit_cast(float, sv[0] & 0xffff0000u);
        float s2 = __builtin_bit_cast(float, sv[1] << 16);
        float s3 = __builtin_bit_cast(float, sv[1] & 0xffff0000u);
        float s4 = __builtin_bit_cast(float, sv[2] << 16);
        float s5 = __builtin_bit_cast(float, sv[2] & 0xffff0000u);
        float s6 = __builtin_bit_cast(float, sv[3] << 16);
        float s7 = __builtin_bit_cast(float, sv[3] & 0xffff0000u);
        u32x4 pv;
        pv[0] = pack2(c0, c1); pv[1] = pack2(c2, c3);
        pv[2] = pack2(c4, c5); pv[3] = pack2(c6, c7);
        *p = pv;
        float d = cd[c];
        c0 = c0 * d + s0; c1 = c1 * d + s1;
        c2 = c2 * d + s2; c3 = c3 * d + s3;
        c4 = c4 * d + s4; c5 = c5 * d + s5;
        c6 = c6 * d + s6; c7 = c7 * d + s7;
    }
}

// ---------------- SSD phase D: Ydiag + Yoff + D*x via MFMA ----------------
__global__ __launch_bounds__(256) void ssd_out(
    const bf16* __restrict__ xin, const bf16* __restrict__ Cm,
    const float* __restrict__ dtT, const float* __restrict__ Gp,
    const bf16* __restrict__ prev, const float* __restrict__ A_log,
    const float* __restrict__ Dv, bf16* __restrict__ y, int nhp, int hs)
{
    const int blk = blockIdx.x;   // bh*NC + c
    const int c = blk & 63, bh = blk >> 6;
    const int hh = bh % nhp, b = bh / nhp;
    const int h = hs * nhp + hh;
    const int tok0 = b * L_ + c * CH;
    const int tid = threadIdx.x, lane = tid & 63, w = tid >> 6;
    const float Ah = -expf(A_log[h]);
    const float Dh = Dv[h];

    __shared__ bf16 Csh[32 * 136];
    __shared__ bf16 prevB[64 * 136];
    __shared__ bf16 GtB[32 * 40];
    __shared__ bf16 xTB[64 * 40];
    __shared__ float dts[32], acum[32], ea[32];

    if (tid < 32) dts[tid] = dtT[((size_t)(b * NH + h)) * L_ + c * CH + tid];
    __syncthreads();
    if (tid < 32) { float s = 0.f; for (int i = 0; i <= tid; ++i) s += dts[i]; acum[tid] = s * Ah; }
    __syncthreads();
    if (tid < 32) ea[tid] = expf(acum[tid]);
    for (int i = tid; i < 4096; i += 256) {
        int l = i >> 7, n = i & 127;
        Csh[l * 136 + n] = Cm[(size_t)(tok0 + l) * DS + n];
    }
    const bf16* pv = prev + (size_t)blk * (HD * DS);
    for (int i = tid; i < 8192; i += 256) {
        int p = i >> 7, n = i & 127;
        prevB[p * 136 + n] = (p < HD) ? pv[p * DS + n] : __float2bfloat16(0.f);
    }
    for (int i = tid; i < 2048; i += 256) {
        int s = i >> 6, p = i & 63;
        float v = (p < HD) ? __bfloat162float(xin[(size_t)(tok0 + s) * DI + h * HD + p]) : 0.f;
        xTB[p * 40 + s] = __float2bfloat16(v);
    }
    const float* grow = Gp + ((size_t)((b << 6) + c) << 10);
    for (int i = tid; i < 1024; i += 256) {
        int l = i >> 5, s = i & 31;
        float g = (s <= l) ? grow[i] * expf(acum[l] - acum[s]) * dts[s] : 0.f;
        GtB[l * 40 + s] = __float2bfloat16(g);
    }
    __syncthreads();

    const int lr = lane & 15, kg = lane >> 4;
    short8 bP[4];
#pragma unroll
    for (int kt = 0; kt < 4; ++kt)
        bP[kt] = *reinterpret_cast<const short8*>(&prevB[(w * 16 + lr) * 136 + kt * 32 + kg * 8]);
    short8 bX = *reinterpret_cast<const short8*>(&xTB[(w * 16 + lr) * 40 + kg * 8]);
    f32x4 accO[2] = {}, accD[2] = {};
#pragma unroll
    for (int mt = 0; mt < 2; ++mt) {
#pragma unroll
        for (int kt = 0; kt < 4; ++kt) {
            short8 a = *reinterpret_cast<const short8*>(&Csh[(mt * 16 + lr) * 136 + kt * 32 + kg * 8]);
            accO[mt] = __builtin_amdgcn_mfma_f32_16x16x32_bf16(a, bP[kt], accO[mt], 0, 0, 0);
        }
        short8 ag = *reinterpret_cast<const short8*>(&GtB[(mt * 16 + lr) * 40 + kg * 8]);
        accD[mt] = __builtin_amdgcn_mfma_f32_16x16x32_bf16(ag, bX, accD[mt], 0, 0, 0);
    }
    const int p = w * 16 + lr;
    if (p < HD) {
#pragma unroll
        for (int mt = 0; mt < 2; ++mt)
#pragma unroll
            for (int r = 0; r < 4; ++r) {
                int l = mt * 16 + kg * 4 + r;
                float yv = ea[l] * accO[mt][r] + accD[mt][r]
                         + Dh * __bfloat162float(xTB[p * 40 + l]);
                y[(size_t)(tok0 + l) * DI + h * HD + p] = __float2bfloat16(yv);
            }
    }
}

// ---------------- gated RMSNorm (bf16 z, vectorized x8) ----------------
__global__ __launch_bounds__(256) void gated_norm_kernel(
    const bf16* __restrict__ yin, const bf16* __restrict__ zxb,
    const float* __restrict__ gw, bf16* __restrict__ y2)
{
    const int tok = blockIdx.x;
    const int tid = threadIdx.x;
    __shared__ float red[4];
    const int c0 = tid * 8;          // 168 active lanes cover DI=1344
    float v[8];
    float ss = 0.f;
    if (c0 < DI) {
        short8 yv = *reinterpret_cast<const short8*>(yin + (size_t)tok * DI + c0);
        short8 zv = *reinterpret_cast<const short8*>(zxb + (size_t)tok * DIP + c0);
#pragma unroll
        for (int j = 0; j < 8; ++j) {
            float y = bf2f(yv[j]);
            float z = bf2f(zv[j]);
            float val = y * (z / (1.f + expf(-z)));
            v[j] = val; ss += val * val;
        }
    }
    for (int o = 32; o > 0; o >>= 1) ss += __shfl_down(ss, o, 64);
    if ((tid & 63) == 0) red[tid >> 6] = ss;
    __syncthreads();
    float tot = red[0] + red[1] + red[2] + red[3];
    float r = rsqrtf(tot / (float)DI + 1e-5f);
    if (c0 < DI) {
        short8 o;
#pragma unroll
        for (int j = 0; j < 8; ++j) o[j] = f2bf(v[j] * r * gw[c0 + j]);
        *reinterpret_cast<short8*>(y2 + (size_t)tok * DI + c0) = o;
    }
}

// ---------------- launch ----------------
extern "C" void kernel_launch(void* const* d_in, const int* in_sizes, int n_in,
                              void* d_out, int out_size, void* d_ws, size_t ws_size,
                              hipStream_t stream)
{
    const float* hidden  = (const float*)d_in[0];
    const float* norm_w  = (const float*)d_in[1];
    const float* in_proj = (const float*)d_in[2];
    const float* conv_w  = (const float*)d_in[3];
    const float* conv_b  = (const float*)d_in[4];
    const float* dt_bias = (const float*)d_in[5];
    const float* A_log   = (const float*)d_in[6];
    const float* Dv      = (const float*)d_in[7];
    const float* gnw     = (const float*)d_in[8];
    const float* out_prj = (const float*)d_in[9];
    float* out = (float*)d_out;

    char* ws = (char*)d_ws;
    bf16*  w1b   = (bf16*)(ws + OFF_W1);
    bf16*  w2b   = (bf16*)(ws + OFF_W2);
    bf16*  xb    = (bf16*)(ws + OFF_XB);
    bf16*  zxb   = (bf16*)(ws + OFF_ZX);
    float* dtraw = (float*)(ws + OFF_DTRAW);
    bf16*  xin   = (bf16*)(ws + OFF_XIN);
    bf16*  Bm    = (bf16*)(ws + OFF_BM);
    bf16*  Cm    = (bf16*)(ws + OFF_CM);
    float* dtT   = (float*)(ws + OFF_DTT);
    float* cdec  = (float*)(ws + OFF_CDEC);
    float* Gp    = (float*)(ws + OFF_G);
    bf16*  yb    = (bf16*)(ws + OFF_Y);
    bf16*  y2    = (bf16*)(ws + OFF_Y2);
    bf16*  stb   = (bf16*)(ws + OFF_ST);

    const int npass = (ws_size >= ST_ONEPASS_END) ? 1 : 2;
    const int nhp = NH / npass;

    cast_weights<<<11319, 256, 0, stream>>>(in_proj, out_prj, w1b, w2b);
    rmsnorm_kernel<<<NTOK, 256, 0, stream>>>(hidden, norm_w, xb);
    gemm1_bf16<<<dim3(NTOK / 256, (DIP + 127) / 128), 512, 0, stream>>>(
        xb, w1b, zxb, dtraw, NTOK, DIP, DM);
    conv_kernel<<<NTOK, 256, 0, stream>>>(zxb, conv_w, conv_b, dtraw, dt_bias,
                                          xin, Bm, Cm, dtT);
    g_mfma<<<B_ * NC, 256, 0, stream>>>(Bm, Cm, Gp);
    for (int hs = 0; hs < npass; ++hs) {
        ssd_states<<<B_ * nhp * NC, 256, 0, stream>>>(xin, Bm, dtT, A_log, stb, cdec, nhp, hs);
        ssd_scan<<<B_ * nhp * 7, 128, 0, stream>>>(stb, cdec, nhp, hs);
        ssd_out<<<B_ * nhp * NC, 256, 0, stream>>>(xin, Cm, dtT, Gp, stb, A_log, Dv, yb, nhp, hs);
    }
    gated_norm_kernel<<<NTOK, 256, 0, stream>>>(yb, zxb, gnw, y2);
    gemm2_bt<<<dim3(NTOK / 128, (DM + 63) / 64), 128, 0, stream>>>(
        y2, w2b, hidden, out, NTOK, DM, DI);
}

// Round 14
// 273.426 us; speedup vs baseline: 1.2560x; 1.2560x over previous
//
#include <hip/hip_runtime.h>
#include <hip/hip_bf16.h>

// ---------------- problem constants ----------------
#define B_    4
#define L_    2048
#define DM    672
#define DI    1344
#define DS    128
#define NH    24
#define HD    56
#define CH    32
#define NC    64
#define DIP   2968
#define CD    1600
#define NTOK  (B_*L_)

typedef __attribute__((ext_vector_type(8))) short short8;
typedef __attribute__((ext_vector_type(4))) float f32x4;
typedef __hip_bfloat16 bf16;

// ---------------- workspace layout (bytes) ----------------
static constexpr size_t OFF_W1   = 0;            // bf16 [2968][672]
static constexpr size_t OFF_W2   = 3989504;      // bf16 [672][1344]
static constexpr size_t OFF_XB   = 5795840;      // bf16 [8192][672]
static constexpr size_t OFF_ZX   = 16805888;     // bf16 [8192][2968] (48.6MB)
static constexpr size_t OFF_DTRAW= 65433600;     // f32  [8192][24] raw dt accums
static constexpr size_t OFF_XIN  = 114061312;    // bf16 [8192][1344]
static constexpr size_t OFF_BM   = 136081408;    // bf16 [8192][128]
static constexpr size_t OFF_CM   = 138178560;    // bf16 [8192][128]
static constexpr size_t OFF_DTT  = 140275712;    // f32  [B][NH][L]
static constexpr size_t OFF_CDEC = 141062144;    // f32  [B][NH][NC]
static constexpr size_t OFF_G    = 141086720;    // f32  [B*NC][1024]
static constexpr size_t OFF_Y    = 142135296;    // bf16 [8192][1344]
static constexpr size_t OFF_Y2   = 164155392;    // bf16 [8192][1344]
static constexpr size_t OFF_ST   = 186175488;    // bf16 states: 44MB (2-pass) or 88MB (1-pass)
static constexpr size_t ST_ONEPASS_END = OFF_ST + (size_t)B_ * NH * NC * HD * DS * 2; // 274MB

__device__ __forceinline__ void gload16(const bf16* g, bf16* l) {
    __builtin_amdgcn_global_load_lds(
        (const __attribute__((address_space(1))) unsigned int*)g,
        (__attribute__((address_space(3))) unsigned int*)l, 16, 0, 0);
}
__device__ __forceinline__ float bf2f(short s) {
    unsigned int u = ((unsigned int)(unsigned short)s) << 16;
    return __builtin_bit_cast(float, u);
}
__device__ __forceinline__ short f2bf(float f) {
    bf16 h = __float2bfloat16(f);
    return *reinterpret_cast<short*>(&h);
}

// ---------------- weight cast ----------------
__global__ __launch_bounds__(256) void cast_weights(
    const float* __restrict__ w1, const float* __restrict__ w2,
    bf16* __restrict__ w1b, bf16* __restrict__ w2b)
{
    int i = blockIdx.x * 256 + threadIdx.x;
    const int W1N = DIP * DM;
    const int W2N = DM * DI;
    if (i < W1N) w1b[i] = __float2bfloat16(w1[i]);
    int j = i - W1N;
    if (j >= 0 && j < W2N) w2b[j] = __float2bfloat16(w2[j]);
}

// ---------------- input RMSNorm + cast to bf16 ----------------
__global__ __launch_bounds__(256) void rmsnorm_kernel(
    const float* __restrict__ in, const float* __restrict__ w,
    bf16* __restrict__ out)
{
    const int tok = blockIdx.x;
    const int tid = threadIdx.x;
    __shared__ float red[4];
    float v[3];
    float ss = 0.f;
    int idx = tid;
#pragma unroll
    for (int j = 0; j < 3; ++j) {
        float x = 0.f;
        if (idx < DM) x = in[(size_t)tok * DM + idx];
        v[j] = x; ss += x * x;
        idx += 256;
    }
    for (int o = 32; o > 0; o >>= 1) ss += __shfl_down(ss, o, 64);
    if ((tid & 63) == 0) red[tid >> 6] = ss;
    __syncthreads();
    float tot = red[0] + red[1] + red[2] + red[3];
    float r = rsqrtf(tot / (float)DM + 1e-5f);
    idx = tid;
#pragma unroll
    for (int j = 0; j < 3; ++j) {
        if (idx < DM) out[(size_t)tok * DM + idx] = __float2bfloat16(v[j] * r * w[idx]);
        idx += 256;
    }
}

// ---------------- GEMM1: 128x128, 4 waves, dbuf gload-lds, bf16 epilogue (R12-proven 59us)
__global__ __launch_bounds__(256) void gemm1_bf16(
    const bf16* __restrict__ A, const bf16* __restrict__ W,
    bf16* __restrict__ Co, float* __restrict__ dtraw,
    int M, int N, int K)
{
    __shared__ bf16 As[2 * 128 * 32];
    __shared__ bf16 Bs[2 * 128 * 32];
    const int tid = threadIdx.x, lane = tid & 63, w = tid >> 6;
    const int wm = w >> 1, wn = w & 1;
    const int m0 = blockIdx.x * 128, n0 = blockIdx.y * 128;
    const int lr = lane & 15, kg = lane >> 4;
    f32x4 acc[4][4] = {};

    const int sr = w * 32 + (lane >> 2);
    const int sc = (lane & 3) * 8;
    const bf16* ga0 = A + (size_t)(m0 + sr) * K + sc;
    const bf16* ga1 = ga0 + (size_t)16 * K;
    int nr0 = n0 + sr;      if (nr0 >= N) nr0 = N - 1;
    int nr1 = n0 + sr + 16; if (nr1 >= N) nr1 = N - 1;
    const bf16* gb0 = W + (size_t)nr0 * K + sc;
    const bf16* gb1 = W + (size_t)nr1 * K + sc;
    bf16* la = &As[w * 1024];
    bf16* lb = &Bs[w * 1024];

    const int nK = K >> 5;
    gload16(ga0, la); gload16(ga1, la + 512);
    gload16(gb0, lb); gload16(gb1, lb + 512);
    ga0 += 32; ga1 += 32; gb0 += 32; gb1 += 32;

    int cur = 0;
    for (int kt = 0; kt < nK; ++kt) {
        __syncthreads();
        if (kt + 1 < nK) {
            const int nb = (cur ^ 1) << 12;
            gload16(ga0, la + nb); gload16(ga1, la + nb + 512);
            gload16(gb0, lb + nb); gload16(gb1, lb + nb + 512);
            ga0 += 32; ga1 += 32; gb0 += 32; gb1 += 32;
        }
        const bf16* Ab = &As[cur << 12];
        const bf16* Bb = &Bs[cur << 12];
        short8 af[4], bfr[4];
#pragma unroll
        for (int i = 0; i < 4; ++i) {
            af[i]  = *reinterpret_cast<const short8*>(&Ab[(wm * 64 + i * 16 + lr) * 32 + kg * 8]);
            bfr[i] = *reinterpret_cast<const short8*>(&Bb[(wn * 64 + i * 16 + lr) * 32 + kg * 8]);
        }
#pragma unroll
        for (int i = 0; i < 4; ++i)
#pragma unroll
            for (int j = 0; j < 4; ++j)
                acc[i][j] = __builtin_amdgcn_mfma_f32_16x16x32_bf16(af[i], bfr[j], acc[i][j], 0, 0, 0);
        cur ^= 1;
    }
    // pure bf16 epilogue
#pragma unroll
    for (int i = 0; i < 4; ++i) {
        int row = m0 + wm * 64 + i * 16 + kg * 4;
#pragma unroll
        for (int j = 0; j < 4; ++j) {
            int col = n0 + wn * 64 + j * 16 + lr;
            if (col < N) {
#pragma unroll
                for (int r = 0; r < 4; ++r)
                    Co[(size_t)(row + r) * N + col] = __float2bfloat16(acc[i][j][r]);
            }
        }
    }
    // cold, block-uniform: raw f32 dt accums for cols [DI+CD, DI+CD+NH)
    if (blockIdx.y == (DI + CD) / 128) {
#pragma unroll
        for (int i = 0; i < 4; ++i) {
            int row = m0 + wm * 64 + i * 16 + kg * 4;
#pragma unroll
            for (int j = 0; j < 4; ++j) {
                int d = wn * 64 + j * 16 + lr;   // n0 == DI+CD exactly
                if (d < NH) {
#pragma unroll
                    for (int r = 0; r < 4; ++r)
                        dtraw[(size_t)(row + r) * NH + d] = acc[i][j][r];
                }
            }
        }
    }
}

// ---------------- GEMM2: 128x64 tile, 2 waves, f32+resid out (R11-proven) ----------
__global__ __launch_bounds__(128) void gemm2_bt(
    const bf16* __restrict__ A, const bf16* __restrict__ W,
    const float* __restrict__ resid, float* __restrict__ Co,
    int M, int N, int K)
{
    __shared__ bf16 As[2 * 128 * 32];
    __shared__ bf16 Bs[2 * 64 * 32];
    const int tid = threadIdx.x, lane = tid & 63, w = tid >> 6;
    const int m0 = blockIdx.x * 128, n0 = blockIdx.y * 64;
    const int lr = lane & 15, kg = lane >> 4;
    f32x4 acc[4][4] = {};

    const int sr = lane >> 2;
    const int sc = (lane & 3) * 8;
    const bf16* ga[4];
#pragma unroll
    for (int i = 0; i < 4; ++i)
        ga[i] = A + (size_t)(m0 + w * 64 + i * 16 + sr) * K + sc;
    const bf16* gb[2];
#pragma unroll
    for (int j = 0; j < 2; ++j) {
        int nr = n0 + w * 32 + j * 16 + sr;
        if (nr >= N) nr = N - 1;
        gb[j] = W + (size_t)nr * K + sc;
    }
    bf16* laB = &As[w * 2048];
    bf16* lbB = &Bs[w * 1024];

    const int nK = K >> 5;
#pragma unroll
    for (int i = 0; i < 4; ++i) gload16(ga[i], laB + i * 512);
#pragma unroll
    for (int j = 0; j < 2; ++j) gload16(gb[j], lbB + j * 512);
#pragma unroll
    for (int i = 0; i < 4; ++i) ga[i] += 32;
#pragma unroll
    for (int j = 0; j < 2; ++j) gb[j] += 32;

    int cur = 0;
    for (int kt = 0; kt < nK; ++kt) {
        __syncthreads();
        if (kt + 1 < nK) {
            const int nbA = (cur ^ 1) * 4096, nbB = (cur ^ 1) * 2048;
#pragma unroll
            for (int i = 0; i < 4; ++i) gload16(ga[i], laB + nbA + i * 512);
#pragma unroll
            for (int j = 0; j < 2; ++j) gload16(gb[j], lbB + nbB + j * 512);
#pragma unroll
            for (int i = 0; i < 4; ++i) ga[i] += 32;
#pragma unroll
            for (int j = 0; j < 2; ++j) gb[j] += 32;
        }
        const bf16* Ab = &As[cur * 4096];
        const bf16* Bb = &Bs[cur * 2048];
        short8 af[4], bfr[4];
#pragma unroll
        for (int i = 0; i < 4; ++i)
            af[i] = *reinterpret_cast<const short8*>(&Ab[(w * 64 + i * 16 + lr) * 32 + kg * 8]);
#pragma unroll
        for (int j = 0; j < 4; ++j)
            bfr[j] = *reinterpret_cast<const short8*>(&Bb[(j * 16 + lr) * 32 + kg * 8]);
#pragma unroll
        for (int i = 0; i < 4; ++i)
#pragma unroll
            for (int j = 0; j < 4; ++j)
                acc[i][j] = __builtin_amdgcn_mfma_f32_16x16x32_bf16(af[i], bfr[j], acc[i][j], 0, 0, 0);
        cur ^= 1;
    }
#pragma unroll
    for (int i = 0; i < 4; ++i) {
        int row = m0 + w * 64 + i * 16 + kg * 4;
#pragma unroll
        for (int j = 0; j < 4; ++j) {
            int col = n0 + j * 16 + lr;
            if (col < N) {
#pragma unroll
                for (int r = 0; r < 4; ++r) {
                    size_t o = (size_t)(row + r) * N + col;
                    Co[o] = acc[i][j][r] + resid[o];
                }
            }
        }
    }
}

// ---------------- conv1d(4, causal, depthwise) + SiLU (bf16 in, x8) + dt ---------
__global__ __launch_bounds__(256) void conv_kernel(
    const bf16* __restrict__ zxb, const float* __restrict__ cw,
    const float* __restrict__ cb, const float* __restrict__ dtraw,
    const float* __restrict__ dtb,
    bf16* __restrict__ xin, bf16* __restrict__ Bm, bf16* __restrict__ Cm,
    float* __restrict__ dtT)      // [B][NH][L]
{
    const int tok = blockIdx.x;
    const int l = tok & (L_ - 1);
    const int tid = threadIdx.x;
    if (tid < 200) {
        const int ch0 = tid * 8;
        float xv[4][8];
#pragma unroll
        for (int k = 0; k < 4; ++k) {
            int li = l - 3 + k;
            if (li >= 0) {
                short8 v = *reinterpret_cast<const short8*>(
                    zxb + (size_t)(tok - 3 + k) * DIP + DI + ch0);
#pragma unroll
                for (int j = 0; j < 8; ++j) xv[k][j] = bf2f(v[j]);
            } else {
#pragma unroll
                for (int j = 0; j < 8; ++j) xv[k][j] = 0.f;
            }
        }
        const f32x4* cw4 = reinterpret_cast<const f32x4*>(cw + ch0 * 4);
        short8 o;
#pragma unroll
        for (int j = 0; j < 8; ++j) {
            f32x4 wv = cw4[j];
            float acc = cb[ch0 + j];
#pragma unroll
            for (int k = 0; k < 4; ++k) acc += xv[k][j] * wv[k];
            acc = acc / (1.f + expf(-acc));
            o[j] = f2bf(acc);
        }
        if (ch0 < DI)
            *reinterpret_cast<short8*>(xin + (size_t)tok * DI + ch0) = o;
        else if (ch0 < DI + DS)
            *reinterpret_cast<short8*>(Bm + (size_t)tok * DS + (ch0 - DI)) = o;
        else
            *reinterpret_cast<short8*>(Cm + (size_t)tok * DS + (ch0 - DI - DS)) = o;
    } else if (tid < 200 + NH) {
        const int hh = tid - 200;
        float v = dtraw[(size_t)tok * NH + hh] + dtb[hh];
        float sp = (v > 20.f) ? v : log1pf(expf(v));
        dtT[((size_t)((tok >> 11) * NH + hh)) * L_ + l] = sp;
    }
}

// ---------------- G = C.B^T per (b,chunk) via MFMA ----------------
__global__ __launch_bounds__(256) void g_mfma(
    const bf16* __restrict__ Bm, const bf16* __restrict__ Cm,
    float* __restrict__ Gp)
{
    const int bc = blockIdx.x;
    const int tok0 = (bc >> 6) * L_ + (bc & 63) * CH;
    const int tid = threadIdx.x, lane = tid & 63, w = tid >> 6;
    __shared__ bf16 Csh[32 * 136], Bsh[32 * 136];
    for (int i = tid; i < 4096; i += 256) {
        int l = i >> 7, n = i & 127;
        Csh[l * 136 + n] = Cm[(size_t)(tok0 + l) * DS + n];
        Bsh[l * 136 + n] = Bm[(size_t)(tok0 + l) * DS + n];
    }
    __syncthreads();
    const int mt = w >> 1, nt = w & 1;
    const int lr = lane & 15, kg = lane >> 4;
    f32x4 acc = {};
#pragma unroll
    for (int kt = 0; kt < 4; ++kt) {
        short8 a = *reinterpret_cast<const short8*>(&Csh[(mt * 16 + lr) * 136 + kt * 32 + kg * 8]);
        short8 b = *reinterpret_cast<const short8*>(&Bsh[(nt * 16 + lr) * 136 + kt * 32 + kg * 8]);
        acc = __builtin_amdgcn_mfma_f32_16x16x32_bf16(a, b, acc, 0, 0, 0);
    }
#pragma unroll
    for (int r = 0; r < 4; ++r) {
        int l = mt * 16 + kg * 4 + r, s = nt * 16 + lr;
        Gp[((size_t)bc << 10) + l * 32 + s] = acc[r];
    }
}

// ---------------- SSD phase B: per-chunk states via MFMA ----------------
__global__ __launch_bounds__(256) void ssd_states(
    const bf16* __restrict__ xin, const bf16* __restrict__ Bm,
    const float* __restrict__ dtT, const float* __restrict__ A_log,
    bf16* __restrict__ st, float* __restrict__ cdec, int nhp, int hs)
{
    const int blk = blockIdx.x;          // bh*NC + c
    const int c = blk & 63, bh = blk >> 6;
    const int hh = bh % nhp, b = bh / nhp;
    const int h = hs * nhp + hh;
    const int tok0 = b * L_ + c * CH;
    const int tid = threadIdx.x, lane = tid & 63, w = tid >> 6;
    const float Ah = -expf(A_log[h]);

    __shared__ bf16 xwT[64 * 40];
    __shared__ bf16 BmT[128 * 40];
    __shared__ float dts[32], acum[32], wdec[32];

    if (tid < 32) dts[tid] = dtT[((size_t)(b * NH + h)) * L_ + c * CH + tid];
    __syncthreads();
    if (tid < 32) { float s = 0.f; for (int i = 0; i <= tid; ++i) s += dts[i]; acum[tid] = s * Ah; }
    __syncthreads();
    if (tid < 32) wdec[tid] = expf(acum[31] - acum[tid]) * dts[tid];
    if (tid == 0) cdec[(size_t)(b * NH + h) * NC + c] = expf(acum[31]);
    for (int i = tid; i < 4096; i += 256) {
        int l = i >> 7, n = i & 127;
        BmT[n * 40 + l] = Bm[(size_t)(tok0 + l) * DS + n];
    }
    __syncthreads();
    for (int i = tid; i < 2048; i += 256) {
        int l = i >> 6, p = i & 63;
        float v = 0.f;
        if (p < HD) v = __bfloat162float(xin[(size_t)(tok0 + l) * DI + h * HD + p]) * wdec[l];
        xwT[p * 40 + l] = __float2bfloat16(v);
    }
    __syncthreads();

    const int lr = lane & 15, kg = lane >> 4;
    const int nt0 = w * 2;
    f32x4 acc[4][2] = {};
    short8 af[4], bfr[2];
#pragma unroll
    for (int mt = 0; mt < 4; ++mt)
        af[mt] = *reinterpret_cast<const short8*>(&xwT[(mt * 16 + lr) * 40 + kg * 8]);
#pragma unroll
    for (int j = 0; j < 2; ++j)
        bfr[j] = *reinterpret_cast<const short8*>(&BmT[((nt0 + j) * 16 + lr) * 40 + kg * 8]);
#pragma unroll
    for (int mt = 0; mt < 4; ++mt)
#pragma unroll
        for (int j = 0; j < 2; ++j)
            acc[mt][j] = __builtin_amdgcn_mfma_f32_16x16x32_bf16(af[mt], bfr[j], acc[mt][j], 0, 0, 0);

    bf16* sb = st + (size_t)blk * (HD * DS);
#pragma unroll
    for (int mt = 0; mt < 4; ++mt)
#pragma unroll
        for (int j = 0; j < 2; ++j) {
            int n = (nt0 + j) * 16 + lr;
#pragma unroll
            for (int r = 0; r < 4; ++r) {
                int p = mt * 16 + kg * 4 + r;
                if (p < HD) sb[p * DS + n] = __float2bfloat16(acc[mt][j][r]);
            }
        }
}

// ---------------- SSD phase C: in-place scan over chunks (R12-proven) ----------
__global__ __launch_bounds__(256) void ssd_scan(
    bf16* __restrict__ st, const float* __restrict__ cdec, int nhp, int hs)
{
    const int blk = blockIdx.x;   // bh*14 + sl
    const int sl = blk % 14;
    const int bh = blk / 14;
    const int b = bh / nhp, hh = bh % nhp;
    const int h = hs * nhp + hh;
    const int e = sl * 512 + threadIdx.x * 2;
    bf16* base = st + (size_t)bh * NC * (HD * DS) + e;
    const float* cd = cdec + (size_t)(b * NH + h) * NC;
    float c0 = 0.f, c1 = 0.f;
    for (int c = 0; c < NC; ++c) {
        unsigned int* p = reinterpret_cast<unsigned int*>(base + (size_t)c * (HD * DS));
        unsigned int sv = *p;
        float s0 = __builtin_bit_cast(float, sv << 16);
        float s1 = __builtin_bit_cast(float, sv & 0xffff0000u);
        bf16 h0 = __float2bfloat16(c0), h1 = __float2bfloat16(c1);
        unsigned int pvw = (unsigned int)*reinterpret_cast<unsigned short*>(&h0)
                         | ((unsigned int)*reinterpret_cast<unsigned short*>(&h1) << 16);
        *p = pvw;
        float d = cd[c];
        c0 = c0 * d + s0;
        c1 = c1 * d + s1;
    }
}

// ---------------- SSD phase D: Ydiag + Yoff + D*x via MFMA ----------------
// prev (B-operand) has ZERO intra-block reuse -> load fragments directly from
// global (skips 17KB LDS staging; LDS 33.5->16.5KB, occupancy ~2x).
__global__ __launch_bounds__(256) void ssd_out(
    const bf16* __restrict__ xin, const bf16* __restrict__ Cm,
    const float* __restrict__ dtT, const float* __restrict__ Gp,
    const bf16* __restrict__ prev, const float* __restrict__ A_log,
    const float* __restrict__ Dv, bf16* __restrict__ y, int nhp, int hs)
{
    const int blk = blockIdx.x;   // bh*NC + c
    const int c = blk & 63, bh = blk >> 6;
    const int hh = bh % nhp, b = bh / nhp;
    const int h = hs * nhp + hh;
    const int tok0 = b * L_ + c * CH;
    const int tid = threadIdx.x, lane = tid & 63, w = tid >> 6;
    const float Ah = -expf(A_log[h]);
    const float Dh = Dv[h];
    const int lr = lane & 15, kg = lane >> 4;
    const int p = w * 16 + lr;    // output headdim index (B-operand row)

    __shared__ bf16 Csh[32 * 136];
    __shared__ bf16 GtB[32 * 40];
    __shared__ bf16 xTB[64 * 40];
    __shared__ float dts[32], acum[32], ea[32];

    // direct global B-fragments of prev[p][n] (each element consumed once)
    const bf16* pv = prev + (size_t)blk * (HD * DS);
    short8 z8 = {0, 0, 0, 0, 0, 0, 0, 0};
    short8 bP[4] = {z8, z8, z8, z8};
    if (p < HD) {
#pragma unroll
        for (int kt = 0; kt < 4; ++kt)
            bP[kt] = *reinterpret_cast<const short8*>(pv + p * DS + kt * 32 + kg * 8);
    }

    if (tid < 32) dts[tid] = dtT[((size_t)(b * NH + h)) * L_ + c * CH + tid];
    __syncthreads();
    if (tid < 32) { float s = 0.f; for (int i = 0; i <= tid; ++i) s += dts[i]; acum[tid] = s * Ah; }
    __syncthreads();
    if (tid < 32) ea[tid] = expf(acum[tid]);
    for (int i = tid; i < 4096; i += 256) {
        int l = i >> 7, n = i & 127;
        Csh[l * 136 + n] = Cm[(size_t)(tok0 + l) * DS + n];
    }
    for (int i = tid; i < 2048; i += 256) {
        int s = i >> 6, pp = i & 63;
        float v = (pp < HD) ? __bfloat162float(xin[(size_t)(tok0 + s) * DI + h * HD + pp]) : 0.f;
        xTB[pp * 40 + s] = __float2bfloat16(v);
    }
    const float* grow = Gp + ((size_t)((b << 6) + c) << 10);
    for (int i = tid; i < 1024; i += 256) {
        int l = i >> 5, s = i & 31;
        float g = (s <= l) ? grow[i] * expf(acum[l] - acum[s]) * dts[s] : 0.f;
        GtB[l * 40 + s] = __float2bfloat16(g);
    }
    __syncthreads();

    short8 bX = *reinterpret_cast<const short8*>(&xTB[(w * 16 + lr) * 40 + kg * 8]);
    f32x4 accO[2] = {}, accD[2] = {};
#pragma unroll
    for (int mt = 0; mt < 2; ++mt) {
#pragma unroll
        for (int kt = 0; kt < 4; ++kt) {
            short8 a = *reinterpret_cast<const short8*>(&Csh[(mt * 16 + lr) * 136 + kt * 32 + kg * 8]);
            accO[mt] = __builtin_amdgcn_mfma_f32_16x16x32_bf16(a, bP[kt], accO[mt], 0, 0, 0);
        }
        short8 ag = *reinterpret_cast<const short8*>(&GtB[(mt * 16 + lr) * 40 + kg * 8]);
        accD[mt] = __builtin_amdgcn_mfma_f32_16x16x32_bf16(ag, bX, accD[mt], 0, 0, 0);
    }
    if (p < HD) {
#pragma unroll
        for (int mt = 0; mt < 2; ++mt)
#pragma unroll
            for (int r = 0; r < 4; ++r) {
                int l = mt * 16 + kg * 4 + r;
                float yv = ea[l] * accO[mt][r] + accD[mt][r]
                         + Dh * __bfloat162float(xTB[p * 40 + l]);
                y[(size_t)(tok0 + l) * DI + h * HD + p] = __float2bfloat16(yv);
            }
    }
}

// ---------------- gated RMSNorm (bf16 z, vectorized x8) ----------------
__global__ __launch_bounds__(256) void gated_norm_kernel(
    const bf16* __restrict__ yin, const bf16* __restrict__ zxb,
    const float* __restrict__ gw, bf16* __restrict__ y2)
{
    const int tok = blockIdx.x;
    const int tid = threadIdx.x;
    __shared__ float red[4];
    const int c0 = tid * 8;          // 168 active lanes cover DI=1344
    float v[8];
    float ss = 0.f;
    if (c0 < DI) {
        short8 yv = *reinterpret_cast<const short8*>(yin + (size_t)tok * DI + c0);
        short8 zv = *reinterpret_cast<const short8*>(zxb + (size_t)tok * DIP + c0);
#pragma unroll
        for (int j = 0; j < 8; ++j) {
            float y = bf2f(yv[j]);
            float z = bf2f(zv[j]);
            float val = y * (z / (1.f + expf(-z)));
            v[j] = val; ss += val * val;
        }
    }
    for (int o = 32; o > 0; o >>= 1) ss += __shfl_down(ss, o, 64);
    if ((tid & 63) == 0) red[tid >> 6] = ss;
    __syncthreads();
    float tot = red[0] + red[1] + red[2] + red[3];
    float r = rsqrtf(tot / (float)DI + 1e-5f);
    if (c0 < DI) {
        short8 o;
#pragma unroll
        for (int j = 0; j < 8; ++j) o[j] = f2bf(v[j] * r * gw[c0 + j]);
        *reinterpret_cast<short8*>(y2 + (size_t)tok * DI + c0) = o;
    }
}

// ---------------- launch ----------------
extern "C" void kernel_launch(void* const* d_in, const int* in_sizes, int n_in,
                              void* d_out, int out_size, void* d_ws, size_t ws_size,
                              hipStream_t stream)
{
    const float* hidden  = (const float*)d_in[0];
    const float* norm_w  = (const float*)d_in[1];
    const float* in_proj = (const float*)d_in[2];
    const float* conv_w  = (const float*)d_in[3];
    const float* conv_b  = (const float*)d_in[4];
    const float* dt_bias = (const float*)d_in[5];
    const float* A_log   = (const float*)d_in[6];
    const float* Dv      = (const float*)d_in[7];
    const float* gnw     = (const float*)d_in[8];
    const float* out_prj = (const float*)d_in[9];
    float* out = (float*)d_out;

    char* ws = (char*)d_ws;
    bf16*  w1b   = (bf16*)(ws + OFF_W1);
    bf16*  w2b   = (bf16*)(ws + OFF_W2);
    bf16*  xb    = (bf16*)(ws + OFF_XB);
    bf16*  zxb   = (bf16*)(ws + OFF_ZX);
    float* dtraw = (float*)(ws + OFF_DTRAW);
    bf16*  xin   = (bf16*)(ws + OFF_XIN);
    bf16*  Bm    = (bf16*)(ws + OFF_BM);
    bf16*  Cm    = (bf16*)(ws + OFF_CM);
    float* dtT   = (float*)(ws + OFF_DTT);
    float* cdec  = (float*)(ws + OFF_CDEC);
    float* Gp    = (float*)(ws + OFF_G);
    bf16*  yb    = (bf16*)(ws + OFF_Y);
    bf16*  y2    = (bf16*)(ws + OFF_Y2);
    bf16*  stb   = (bf16*)(ws + OFF_ST);

    const int npass = (ws_size >= ST_ONEPASS_END) ? 1 : 2;
    const int nhp = NH / npass;

    cast_weights<<<11319, 256, 0, stream>>>(in_proj, out_prj, w1b, w2b);
    rmsnorm_kernel<<<NTOK, 256, 0, stream>>>(hidden, norm_w, xb);
    gemm1_bf16<<<dim3(NTOK / 128, (DIP + 127) / 128), 256, 0, stream>>>(
        xb, w1b, zxb, dtraw, NTOK, DIP, DM);
    conv_kernel<<<NTOK, 256, 0, stream>>>(zxb, conv_w, conv_b, dtraw, dt_bias,
                                          xin, Bm, Cm, dtT);
    g_mfma<<<B_ * NC, 256, 0, stream>>>(Bm, Cm, Gp);
    for (int hs = 0; hs < npass; ++hs) {
        ssd_states<<<B_ * nhp * NC, 256, 0, stream>>>(xin, Bm, dtT, A_log, stb, cdec, nhp, hs);
        ssd_scan<<<B_ * nhp * 14, 256, 0, stream>>>(stb, cdec, nhp, hs);
        ssd_out<<<B_ * nhp * NC, 256, 0, stream>>>(xin, Cm, dtT, Gp, stb, A_log, Dv, yb, nhp, hs);
    }
    gated_norm_kernel<<<NTOK, 256, 0, stream>>>(yb, zxb, gnw, y2);
    gemm2_bt<<<dim3(NTOK / 128, (DM + 63) / 64), 128, 0, stream>>>(
        y2, w2b, hidden, out, NTOK, DM, DI);
}

// Round 16
// 267.028 us; speedup vs baseline: 1.2861x; 1.0240x over previous
//
#include <hip/hip_runtime.h>
#include <hip/hip_bf16.h>

// ---------------- problem constants ----------------
#define B_    4
#define L_    2048
#define DM    672
#define DI    1344
#define DS    128
#define NH    24
#define HD    56
#define CH    32
#define NC    64
#define DIP   2968
#define CD    1600
#define NTOK  (B_*L_)

typedef __attribute__((ext_vector_type(8))) short short8;
typedef __attribute__((ext_vector_type(4))) short s16x4;   // (short4 collides with HIP header)
typedef __attribute__((ext_vector_type(4))) float f32x4;
typedef __hip_bfloat16 bf16;

// ---------------- workspace layout (bytes) ----------------
static constexpr size_t OFF_W1   = 0;            // bf16 [2968][672]
static constexpr size_t OFF_W2   = 3989504;      // bf16 [672][1344]
static constexpr size_t OFF_XB   = 5795840;      // bf16 [8192][672]
static constexpr size_t OFF_ZX   = 16805888;     // bf16 [8192][2968] (48.6MB)
static constexpr size_t OFF_DTRAW= 65433600;     // f32  [8192][24] raw dt accums
static constexpr size_t OFF_XIN  = 114061312;    // bf16 [8192][1344]
static constexpr size_t OFF_BM   = 136081408;    // bf16 [8192][128]
static constexpr size_t OFF_CM   = 138178560;    // bf16 [8192][128]
static constexpr size_t OFF_DTT  = 140275712;    // f32  [B][NH][L]
static constexpr size_t OFF_CDEC = 141062144;    // f32  [B][NH][NC]
static constexpr size_t OFF_G    = 141086720;    // f32  [B*NC][1024]
static constexpr size_t OFF_Y    = 142135296;    // bf16 [8192][1344]
static constexpr size_t OFF_Y2   = 164155392;    // bf16 [8192][1344]
static constexpr size_t OFF_ST   = 186175488;    // bf16 states: 44MB (2-pass) or 88MB (1-pass)
static constexpr size_t ST_ONEPASS_END = OFF_ST + (size_t)B_ * NH * NC * HD * DS * 2; // 274MB

__device__ __forceinline__ void gload16(const bf16* g, bf16* l) {
    __builtin_amdgcn_global_load_lds(
        (const __attribute__((address_space(1))) unsigned int*)g,
        (__attribute__((address_space(3))) unsigned int*)l, 16, 0, 0);
}
__device__ __forceinline__ float bf2f(short s) {
    unsigned int u = ((unsigned int)(unsigned short)s) << 16;
    return __builtin_bit_cast(float, u);
}
__device__ __forceinline__ short f2bf(float f) {
    bf16 h = __float2bfloat16(f);
    return *reinterpret_cast<short*>(&h);
}

// ---------------- weight cast (vectorized x4) ----------------
__global__ __launch_bounds__(256) void cast_weights(
    const float* __restrict__ w1, const float* __restrict__ w2,
    bf16* __restrict__ w1b, bf16* __restrict__ w2b)
{
    const int W1N = DIP * DM;   // 1994496 (div 4)
    const int W2N = DM * DI;    // 903168  (div 4)
    int i = (blockIdx.x * 256 + threadIdx.x) * 4;
    if (i < W1N) {
        f32x4 v = *reinterpret_cast<const f32x4*>(w1 + i);
        s16x4 o;
#pragma unroll
        for (int j = 0; j < 4; ++j) o[j] = f2bf(v[j]);
        *reinterpret_cast<s16x4*>(w1b + i) = o;
    } else {
        int j4 = i - W1N;
        if (j4 < W2N) {
            f32x4 v = *reinterpret_cast<const f32x4*>(w2 + j4);
            s16x4 o;
#pragma unroll
            for (int j = 0; j < 4; ++j) o[j] = f2bf(v[j]);
            *reinterpret_cast<s16x4*>(w2b + j4) = o;
        }
    }
}

// ---------------- input RMSNorm + cast to bf16 ----------------
__global__ __launch_bounds__(256) void rmsnorm_kernel(
    const float* __restrict__ in, const float* __restrict__ w,
    bf16* __restrict__ out)
{
    const int tok = blockIdx.x;
    const int tid = threadIdx.x;
    __shared__ float red[4];
    float v[3];
    float ss = 0.f;
    int idx = tid;
#pragma unroll
    for (int j = 0; j < 3; ++j) {
        float x = 0.f;
        if (idx < DM) x = in[(size_t)tok * DM + idx];
        v[j] = x; ss += x * x;
        idx += 256;
    }
    for (int o = 32; o > 0; o >>= 1) ss += __shfl_down(ss, o, 64);
    if ((tid & 63) == 0) red[tid >> 6] = ss;
    __syncthreads();
    float tot = red[0] + red[1] + red[2] + red[3];
    float r = rsqrtf(tot / (float)DM + 1e-5f);
    idx = tid;
#pragma unroll
    for (int j = 0; j < 3; ++j) {
        if (idx < DM) out[(size_t)tok * DM + idx] = __float2bfloat16(v[j] * r * w[idx]);
        idx += 256;
    }
}

// ---------------- GEMM1: 128x128, 4 waves, dbuf gload-lds, bf16 epilogue (R12-proven 59us)
__global__ __launch_bounds__(256) void gemm1_bf16(
    const bf16* __restrict__ A, const bf16* __restrict__ W,
    bf16* __restrict__ Co, float* __restrict__ dtraw,
    int M, int N, int K)
{
    __shared__ bf16 As[2 * 128 * 32];
    __shared__ bf16 Bs[2 * 128 * 32];
    const int tid = threadIdx.x, lane = tid & 63, w = tid >> 6;
    const int wm = w >> 1, wn = w & 1;
    const int m0 = blockIdx.x * 128, n0 = blockIdx.y * 128;
    const int lr = lane & 15, kg = lane >> 4;
    f32x4 acc[4][4] = {};

    const int sr = w * 32 + (lane >> 2);
    const int sc = (lane & 3) * 8;
    const bf16* ga0 = A + (size_t)(m0 + sr) * K + sc;
    const bf16* ga1 = ga0 + (size_t)16 * K;
    int nr0 = n0 + sr;      if (nr0 >= N) nr0 = N - 1;
    int nr1 = n0 + sr + 16; if (nr1 >= N) nr1 = N - 1;
    const bf16* gb0 = W + (size_t)nr0 * K + sc;
    const bf16* gb1 = W + (size_t)nr1 * K + sc;
    bf16* la = &As[w * 1024];
    bf16* lb = &Bs[w * 1024];

    const int nK = K >> 5;
    gload16(ga0, la); gload16(ga1, la + 512);
    gload16(gb0, lb); gload16(gb1, lb + 512);
    ga0 += 32; ga1 += 32; gb0 += 32; gb1 += 32;

    int cur = 0;
    for (int kt = 0; kt < nK; ++kt) {
        __syncthreads();
        if (kt + 1 < nK) {
            const int nb = (cur ^ 1) << 12;
            gload16(ga0, la + nb); gload16(ga1, la + nb + 512);
            gload16(gb0, lb + nb); gload16(gb1, lb + nb + 512);
            ga0 += 32; ga1 += 32; gb0 += 32; gb1 += 32;
        }
        const bf16* Ab = &As[cur << 12];
        const bf16* Bb = &Bs[cur << 12];
        short8 af[4], bfr[4];
#pragma unroll
        for (int i = 0; i < 4; ++i) {
            af[i]  = *reinterpret_cast<const short8*>(&Ab[(wm * 64 + i * 16 + lr) * 32 + kg * 8]);
            bfr[i] = *reinterpret_cast<const short8*>(&Bb[(wn * 64 + i * 16 + lr) * 32 + kg * 8]);
        }
#pragma unroll
        for (int i = 0; i < 4; ++i)
#pragma unroll
            for (int j = 0; j < 4; ++j)
                acc[i][j] = __builtin_amdgcn_mfma_f32_16x16x32_bf16(af[i], bfr[j], acc[i][j], 0, 0, 0);
        cur ^= 1;
    }
    // pure bf16 epilogue
#pragma unroll
    for (int i = 0; i < 4; ++i) {
        int row = m0 + wm * 64 + i * 16 + kg * 4;
#pragma unroll
        for (int j = 0; j < 4; ++j) {
            int col = n0 + wn * 64 + j * 16 + lr;
            if (col < N) {
#pragma unroll
                for (int r = 0; r < 4; ++r)
                    Co[(size_t)(row + r) * N + col] = __float2bfloat16(acc[i][j][r]);
            }
        }
    }
    // cold, block-uniform: raw f32 dt accums for cols [DI+CD, DI+CD+NH)
    if (blockIdx.y == (DI + CD) / 128) {
#pragma unroll
        for (int i = 0; i < 4; ++i) {
            int row = m0 + wm * 64 + i * 16 + kg * 4;
#pragma unroll
            for (int j = 0; j < 4; ++j) {
                int d = wn * 64 + j * 16 + lr;   // n0 == DI+CD exactly
                if (d < NH) {
#pragma unroll
                    for (int r = 0; r < 4; ++r)
                        dtraw[(size_t)(row + r) * NH + d] = acc[i][j][r];
                }
            }
        }
    }
}

// ---------------- GEMM2: 128x64 tile, 4 waves (32x64/wave), f32+resid out ----------
__global__ __launch_bounds__(256) void gemm2_bt(
    const bf16* __restrict__ A, const bf16* __restrict__ W,
    const float* __restrict__ resid, float* __restrict__ Co,
    int M, int N, int K)
{
    __shared__ bf16 As[2 * 128 * 32];   // buffer stride 4096 elems
    __shared__ bf16 Bs[2 * 64 * 32];    // buffer stride 2048 elems
    const int tid = threadIdx.x, lane = tid & 63, w = tid >> 6;  // w 0..3
    const int m0 = blockIdx.x * 128, n0 = blockIdx.y * 64;
    const int lr = lane & 15, kg = lane >> 4;
    f32x4 acc[2][4] = {};

    const int sr = lane >> 2;          // 0..15
    const int sc = (lane & 3) * 8;
    // A: wave w stages rows [w*32, w*32+32) via 2 instrs
    const bf16* ga0 = A + (size_t)(m0 + w * 32 + sr) * K + sc;
    const bf16* ga1 = ga0 + (size_t)16 * K;
    // B: wave w stages rows [w*16, w*16+16) via 1 instr
    int nrB = n0 + w * 16 + sr; if (nrB >= N) nrB = N - 1;
    const bf16* gb0 = W + (size_t)nrB * K + sc;
    bf16* la = &As[w * 1024];   // + buf*4096
    bf16* lb = &Bs[w * 512];    // + buf*2048

    const int nK = K >> 5;   // 42
    gload16(ga0, la); gload16(ga1, la + 512); gload16(gb0, lb);
    ga0 += 32; ga1 += 32; gb0 += 32;

    int cur = 0;
    for (int kt = 0; kt < nK; ++kt) {
        __syncthreads();
        if (kt + 1 < nK) {
            const int nbA = (cur ^ 1) * 4096, nbB = (cur ^ 1) * 2048;
            gload16(ga0, la + nbA); gload16(ga1, la + nbA + 512);
            gload16(gb0, lb + nbB);
            ga0 += 32; ga1 += 32; gb0 += 32;
        }
        const bf16* Ab = &As[cur * 4096];
        const bf16* Bb = &Bs[cur * 2048];
        short8 af[2], bfr[4];
#pragma unroll
        for (int i = 0; i < 2; ++i)
            af[i] = *reinterpret_cast<const short8*>(&Ab[(w * 32 + i * 16 + lr) * 32 + kg * 8]);
#pragma unroll
        for (int j = 0; j < 4; ++j)
            bfr[j] = *reinterpret_cast<const short8*>(&Bb[(j * 16 + lr) * 32 + kg * 8]);
#pragma unroll
        for (int i = 0; i < 2; ++i)
#pragma unroll
            for (int j = 0; j < 4; ++j)
                acc[i][j] = __builtin_amdgcn_mfma_f32_16x16x32_bf16(af[i], bfr[j], acc[i][j], 0, 0, 0);
        cur ^= 1;
    }
#pragma unroll
    for (int i = 0; i < 2; ++i) {
        int row = m0 + w * 32 + i * 16 + kg * 4;
#pragma unroll
        for (int j = 0; j < 4; ++j) {
            int col = n0 + j * 16 + lr;
            if (col < N) {
#pragma unroll
                for (int r = 0; r < 4; ++r) {
                    size_t o = (size_t)(row + r) * N + col;
                    Co[o] = acc[i][j][r] + resid[o];
                }
            }
        }
    }
}

// ---------------- conv1d(4, causal, depthwise) + SiLU (bf16 in, x8) + dt ---------
__global__ __launch_bounds__(256) void conv_kernel(
    const bf16* __restrict__ zxb, const float* __restrict__ cw,
    const float* __restrict__ cb, const float* __restrict__ dtraw,
    const float* __restrict__ dtb,
    bf16* __restrict__ xin, bf16* __restrict__ Bm, bf16* __restrict__ Cm,
    float* __restrict__ dtT)      // [B][NH][L]
{
    const int tok = blockIdx.x;
    const int l = tok & (L_ - 1);
    const int tid = threadIdx.x;
    if (tid < 200) {
        const int ch0 = tid * 8;
        float xv[4][8];
#pragma unroll
        for (int k = 0; k < 4; ++k) {
            int li = l - 3 + k;
            if (li >= 0) {
                short8 v = *reinterpret_cast<const short8*>(
                    zxb + (size_t)(tok - 3 + k) * DIP + DI + ch0);
#pragma unroll
                for (int j = 0; j < 8; ++j) xv[k][j] = bf2f(v[j]);
            } else {
#pragma unroll
                for (int j = 0; j < 8; ++j) xv[k][j] = 0.f;
            }
        }
        const f32x4* cw4 = reinterpret_cast<const f32x4*>(cw + ch0 * 4);
        short8 o;
#pragma unroll
        for (int j = 0; j < 8; ++j) {
            f32x4 wv = cw4[j];
            float acc = cb[ch0 + j];
#pragma unroll
            for (int k = 0; k < 4; ++k) acc += xv[k][j] * wv[k];
            acc = acc / (1.f + expf(-acc));
            o[j] = f2bf(acc);
        }
        if (ch0 < DI)
            *reinterpret_cast<short8*>(xin + (size_t)tok * DI + ch0) = o;
        else if (ch0 < DI + DS)
            *reinterpret_cast<short8*>(Bm + (size_t)tok * DS + (ch0 - DI)) = o;
        else
            *reinterpret_cast<short8*>(Cm + (size_t)tok * DS + (ch0 - DI - DS)) = o;
    } else if (tid < 200 + NH) {
        const int hh = tid - 200;
        float v = dtraw[(size_t)tok * NH + hh] + dtb[hh];
        float sp = (v > 20.f) ? v : log1pf(expf(v));
        dtT[((size_t)((tok >> 11) * NH + hh)) * L_ + l] = sp;
    }
}

// ---------------- G = C.B^T per (b,chunk) via MFMA ----------------
__global__ __launch_bounds__(256) void g_mfma(
    const bf16* __restrict__ Bm, const bf16* __restrict__ Cm,
    float* __restrict__ Gp)
{
    const int bc = blockIdx.x;
    const int tok0 = (bc >> 6) * L_ + (bc & 63) * CH;
    const int tid = threadIdx.x, lane = tid & 63, w = tid >> 6;
    __shared__ bf16 Csh[32 * 136], Bsh[32 * 136];
    for (int i = tid; i < 4096; i += 256) {
        int l = i >> 7, n = i & 127;
        Csh[l * 136 + n] = Cm[(size_t)(tok0 + l) * DS + n];
        Bsh[l * 136 + n] = Bm[(size_t)(tok0 + l) * DS + n];
    }
    __syncthreads();
    const int mt = w >> 1, nt = w & 1;
    const int lr = lane & 15, kg = lane >> 4;
    f32x4 acc = {};
#pragma unroll
    for (int kt = 0; kt < 4; ++kt) {
        short8 a = *reinterpret_cast<const short8*>(&Csh[(mt * 16 + lr) * 136 + kt * 32 + kg * 8]);
        short8 b = *reinterpret_cast<const short8*>(&Bsh[(nt * 16 + lr) * 136 + kt * 32 + kg * 8]);
        acc = __builtin_amdgcn_mfma_f32_16x16x32_bf16(a, b, acc, 0, 0, 0);
    }
#pragma unroll
    for (int r = 0; r < 4; ++r) {
        int l = mt * 16 + kg * 4 + r, s = nt * 16 + lr;
        Gp[((size_t)bc << 10) + l * 32 + s] = acc[r];
    }
}

// ---------------- SSD phase B: per-chunk states via MFMA ----------------
__global__ __launch_bounds__(256) void ssd_states(
    const bf16* __restrict__ xin, const bf16* __restrict__ Bm,
    const float* __restrict__ dtT, const float* __restrict__ A_log,
    bf16* __restrict__ st, float* __restrict__ cdec, int nhp, int hs)
{
    const int blk = blockIdx.x;          // bh*NC + c
    const int c = blk & 63, bh = blk >> 6;
    const int hh = bh % nhp, b = bh / nhp;
    const int h = hs * nhp + hh;
    const int tok0 = b * L_ + c * CH;
    const int tid = threadIdx.x, lane = tid & 63, w = tid >> 6;
    const float Ah = -expf(A_log[h]);

    __shared__ bf16 xwT[64 * 40];
    __shared__ bf16 BmT[128 * 40];
    __shared__ float dts[32], acum[32], wdec[32];

    if (tid < 32) dts[tid] = dtT[((size_t)(b * NH + h)) * L_ + c * CH + tid];
    __syncthreads();
    if (tid < 32) { float s = 0.f; for (int i = 0; i <= tid; ++i) s += dts[i]; acum[tid] = s * Ah; }
    __syncthreads();
    if (tid < 32) wdec[tid] = expf(acum[31] - acum[tid]) * dts[tid];
    if (tid == 0) cdec[(size_t)(b * NH + h) * NC + c] = expf(acum[31]);
    for (int i = tid; i < 4096; i += 256) {
        int l = i >> 7, n = i & 127;
        BmT[n * 40 + l] = Bm[(size_t)(tok0 + l) * DS + n];
    }
    __syncthreads();
    for (int i = tid; i < 2048; i += 256) {
        int l = i >> 6, p = i & 63;
        float v = 0.f;
        if (p < HD) v = __bfloat162float(xin[(size_t)(tok0 + l) * DI + h * HD + p]) * wdec[l];
        xwT[p * 40 + l] = __float2bfloat16(v);
    }
    __syncthreads();

    const int lr = lane & 15, kg = lane >> 4;
    const int nt0 = w * 2;
    f32x4 acc[4][2] = {};
    short8 af[4], bfr[2];
#pragma unroll
    for (int mt = 0; mt < 4; ++mt)
        af[mt] = *reinterpret_cast<const short8*>(&xwT[(mt * 16 + lr) * 40 + kg * 8]);
#pragma unroll
    for (int j = 0; j < 2; ++j)
        bfr[j] = *reinterpret_cast<const short8*>(&BmT[((nt0 + j) * 16 + lr) * 40 + kg * 8]);
#pragma unroll
    for (int mt = 0; mt < 4; ++mt)
#pragma unroll
        for (int j = 0; j < 2; ++j)
            acc[mt][j] = __builtin_amdgcn_mfma_f32_16x16x32_bf16(af[mt], bfr[j], acc[mt][j], 0, 0, 0);

    bf16* sb = st + (size_t)blk * (HD * DS);
#pragma unroll
    for (int mt = 0; mt < 4; ++mt)
#pragma unroll
        for (int j = 0; j < 2; ++j) {
            int n = (nt0 + j) * 16 + lr;
#pragma unroll
            for (int r = 0; r < 4; ++r) {
                int p = mt * 16 + kg * 4 + r;
                if (p < HD) sb[p * DS + n] = __float2bfloat16(acc[mt][j][r]);
            }
        }
}

// ---------------- SSD phase C: in-place scan over chunks (R12-proven) ----------
__global__ __launch_bounds__(256) void ssd_scan(
    bf16* __restrict__ st, const float* __restrict__ cdec, int nhp, int hs)
{
    const int blk = blockIdx.x;   // bh*14 + sl
    const int sl = blk % 14;
    const int bh = blk / 14;
    const int b = bh / nhp, hh = bh % nhp;
    const int h = hs * nhp + hh;
    const int e = sl * 512 + threadIdx.x * 2;
    bf16* base = st + (size_t)bh * NC * (HD * DS) + e;
    const float* cd = cdec + (size_t)(b * NH + h) * NC;
    float c0 = 0.f, c1 = 0.f;
    for (int c = 0; c < NC; ++c) {
        unsigned int* p = reinterpret_cast<unsigned int*>(base + (size_t)c * (HD * DS));
        unsigned int sv = *p;
        float s0 = __builtin_bit_cast(float, sv << 16);
        float s1 = __builtin_bit_cast(float, sv & 0xffff0000u);
        bf16 h0 = __float2bfloat16(c0), h1 = __float2bfloat16(c1);
        unsigned int pvw = (unsigned int)*reinterpret_cast<unsigned short*>(&h0)
                         | ((unsigned int)*reinterpret_cast<unsigned short*>(&h1) << 16);
        *p = pvw;
        float d = cd[c];
        c0 = c0 * d + s0;
        c1 = c1 * d + s1;
    }
}

// ---------------- SSD phase D: Ydiag + Yoff + D*x via MFMA (prev direct-global) ----
__global__ __launch_bounds__(256) void ssd_out(
    const bf16* __restrict__ xin, const bf16* __restrict__ Cm,
    const float* __restrict__ dtT, const float* __restrict__ Gp,
    const bf16* __restrict__ prev, const float* __restrict__ A_log,
    const float* __restrict__ Dv, bf16* __restrict__ y, int nhp, int hs)
{
    const int blk = blockIdx.x;   // bh*NC + c
    const int c = blk & 63, bh = blk >> 6;
    const int hh = bh % nhp, b = bh / nhp;
    const int h = hs * nhp + hh;
    const int tok0 = b * L_ + c * CH;
    const int tid = threadIdx.x, lane = tid & 63, w = tid >> 6;
    const float Ah = -expf(A_log[h]);
    const float Dh = Dv[h];
    const int lr = lane & 15, kg = lane >> 4;
    const int p = w * 16 + lr;    // output headdim index (B-operand row)

    __shared__ bf16 Csh[32 * 136];
    __shared__ bf16 GtB[32 * 40];
    __shared__ bf16 xTB[64 * 40];
    __shared__ float dts[32], acum[32], ea[32];

    // direct global B-fragments of prev[p][n] (each element consumed once)
    const bf16* pv = prev + (size_t)blk * (HD * DS);
    short8 z8 = {0, 0, 0, 0, 0, 0, 0, 0};
    short8 bP[4] = {z8, z8, z8, z8};
    if (p < HD) {
#pragma unroll
        for (int kt = 0; kt < 4; ++kt)
            bP[kt] = *reinterpret_cast<const short8*>(pv + p * DS + kt * 32 + kg * 8);
    }

    if (tid < 32) dts[tid] = dtT[((size_t)(b * NH + h)) * L_ + c * CH + tid];
    __syncthreads();
    if (tid < 32) { float s = 0.f; for (int i = 0; i <= tid; ++i) s += dts[i]; acum[tid] = s * Ah; }
    __syncthreads();
    if (tid < 32) ea[tid] = expf(acum[tid]);
    for (int i = tid; i < 4096; i += 256) {
        int l = i >> 7, n = i & 127;
        Csh[l * 136 + n] = Cm[(size_t)(tok0 + l) * DS + n];
    }
    for (int i = tid; i < 2048; i += 256) {
        int s = i >> 6, pp = i & 63;
        float v = (pp < HD) ? __bfloat162float(xin[(size_t)(tok0 + s) * DI + h * HD + pp]) : 0.f;
        xTB[pp * 40 + s] = __float2bfloat16(v);
    }
    const float* grow = Gp + ((size_t)((b << 6) + c) << 10);
    for (int i = tid; i < 1024; i += 256) {
        int l = i >> 5, s = i & 31;
        float g = (s <= l) ? grow[i] * expf(acum[l] - acum[s]) * dts[s] : 0.f;
        GtB[l * 40 + s] = __float2bfloat16(g);
    }
    __syncthreads();

    short8 bX = *reinterpret_cast<const short8*>(&xTB[(w * 16 + lr) * 40 + kg * 8]);
    f32x4 accO[2] = {}, accD[2] = {};
#pragma unroll
    for (int mt = 0; mt < 2; ++mt) {
#pragma unroll
        for (int kt = 0; kt < 4; ++kt) {
            short8 a = *reinterpret_cast<const short8*>(&Csh[(mt * 16 + lr) * 136 + kt * 32 + kg * 8]);
            accO[mt] = __builtin_amdgcn_mfma_f32_16x16x32_bf16(a, bP[kt], accO[mt], 0, 0, 0);
        }
        short8 ag = *reinterpret_cast<const short8*>(&GtB[(mt * 16 + lr) * 40 + kg * 8]);
        accD[mt] = __builtin_amdgcn_mfma_f32_16x16x32_bf16(ag, bX, accD[mt], 0, 0, 0);
    }
    if (p < HD) {
#pragma unroll
        for (int mt = 0; mt < 2; ++mt)
#pragma unroll
            for (int r = 0; r < 4; ++r) {
                int l = mt * 16 + kg * 4 + r;
                float yv = ea[l] * accO[mt][r] + accD[mt][r]
                         + Dh * __bfloat162float(xTB[p * 40 + l]);
                y[(size_t)(tok0 + l) * DI + h * HD + p] = __float2bfloat16(yv);
            }
    }
}

// ---------------- gated RMSNorm (bf16 z, vectorized x8) ----------------
__global__ __launch_bounds__(256) void gated_norm_kernel(
    const bf16* __restrict__ yin, const bf16* __restrict__ zxb,
    const float* __restrict__ gw, bf16* __restrict__ y2)
{
    const int tok = blockIdx.x;
    const int tid = threadIdx.x;
    __shared__ float red[4];
    const int c0 = tid * 8;          // 168 active lanes cover DI=1344
    float v[8];
    float ss = 0.f;
    if (c0 < DI) {
        short8 yv = *reinterpret_cast<const short8*>(yin + (size_t)tok * DI + c0);
        short8 zv = *reinterpret_cast<const short8*>(zxb + (size_t)tok * DIP + c0);
#pragma unroll
        for (int j = 0; j < 8; ++j) {
            float y = bf2f(yv[j]);
            float z = bf2f(zv[j]);
            float val = y * (z / (1.f + expf(-z)));
            v[j] = val; ss += val * val;
        }
    }
    for (int o = 32; o > 0; o >>= 1) ss += __shfl_down(ss, o, 64);
    if ((tid & 63) == 0) red[tid >> 6] = ss;
    __syncthreads();
    float tot = red[0] + red[1] + red[2] + red[3];
    float r = rsqrtf(tot / (float)DI + 1e-5f);
    if (c0 < DI) {
        short8 o;
#pragma unroll
        for (int j = 0; j < 8; ++j) o[j] = f2bf(v[j] * r * gw[c0 + j]);
        *reinterpret_cast<short8*>(y2 + (size_t)tok * DI + c0) = o;
    }
}

// ---------------- launch ----------------
extern "C" void kernel_launch(void* const* d_in, const int* in_sizes, int n_in,
                              void* d_out, int out_size, void* d_ws, size_t ws_size,
                              hipStream_t stream)
{
    const float* hidden  = (const float*)d_in[0];
    const float* norm_w  = (const float*)d_in[1];
    const float* in_proj = (const float*)d_in[2];
    const float* conv_w  = (const float*)d_in[3];
    const float* conv_b  = (const float*)d_in[4];
    const float* dt_bias = (const float*)d_in[5];
    const float* A_log   = (const float*)d_in[6];
    const float* Dv      = (const float*)d_in[7];
    const float* gnw     = (const float*)d_in[8];
    const float* out_prj = (const float*)d_in[9];
    float* out = (float*)d_out;

    char* ws = (char*)d_ws;
    bf16*  w1b   = (bf16*)(ws + OFF_W1);
    bf16*  w2b   = (bf16*)(ws + OFF_W2);
    bf16*  xb    = (bf16*)(ws + OFF_XB);
    bf16*  zxb   = (bf16*)(ws + OFF_ZX);
    float* dtraw = (float*)(ws + OFF_DTRAW);
    bf16*  xin   = (bf16*)(ws + OFF_XIN);
    bf16*  Bm    = (bf16*)(ws + OFF_BM);
    bf16*  Cm    = (bf16*)(ws + OFF_CM);
    float* dtT   = (float*)(ws + OFF_DTT);
    float* cdec  = (float*)(ws + OFF_CDEC);
    float* Gp    = (float*)(ws + OFF_G);
    bf16*  yb    = (bf16*)(ws + OFF_Y);
    bf16*  y2    = (bf16*)(ws + OFF_Y2);
    bf16*  stb   = (bf16*)(ws + OFF_ST);

    const int npass = (ws_size >= ST_ONEPASS_END) ? 1 : 2;
    const int nhp = NH / npass;

    cast_weights<<<2831, 256, 0, stream>>>(in_proj, out_prj, w1b, w2b);
    rmsnorm_kernel<<<NTOK, 256, 0, stream>>>(hidden, norm_w, xb);
    gemm1_bf16<<<dim3(NTOK / 128, (DIP + 127) / 128), 256, 0, stream>>>(
        xb, w1b, zxb, dtraw, NTOK, DIP, DM);
    conv_kernel<<<NTOK, 256, 0, stream>>>(zxb, conv_w, conv_b, dtraw, dt_bias,
                                          xin, Bm, Cm, dtT);
    g_mfma<<<B_ * NC, 256, 0, stream>>>(Bm, Cm, Gp);
    for (int hs = 0; hs < npass; ++hs) {
        ssd_states<<<B_ * nhp * NC, 256, 0, stream>>>(xin, Bm, dtT, A_log, stb, cdec, nhp, hs);
        ssd_scan<<<B_ * nhp * 14, 256, 0, stream>>>(stb, cdec, nhp, hs);
        ssd_out<<<B_ * nhp * NC, 256, 0, stream>>>(xin, Cm, dtT, Gp, stb, A_log, Dv, yb, nhp, hs);
    }
    gated_norm_kernel<<<NTOK, 256, 0, stream>>>(yb, zxb, gnw, y2);
    gemm2_bt<<<dim3(NTOK / 128, (DM + 63) / 64), 256, 0, stream>>>(
        y2, w2b, hidden, out, NTOK, DM, DI);
}

// Round 18
// 249.530 us; speedup vs baseline: 1.3763x; 1.0701x over previous
//
#include <hip/hip_runtime.h>
#include <hip/hip_bf16.h>

// ---------------- problem constants ----------------
#define B_    4
#define L_    2048
#define DM    672
#define DI    1344
#define DS    128
#define NH    24
#define HD    56
#define CH    32
#define NC    64
#define DIP   2968
#define CD    1600
#define NTOK  (B_*L_)

typedef __attribute__((ext_vector_type(8))) short short8;
typedef __attribute__((ext_vector_type(4))) short s16x4;   // (short4 collides with HIP header)
typedef __attribute__((ext_vector_type(4))) float f32x4;
typedef __hip_bfloat16 bf16;

// ---------------- workspace layout (bytes) ----------------
static constexpr size_t OFF_W1   = 0;            // bf16 [2968][672]
static constexpr size_t OFF_W2   = 3989504;      // bf16 [672][1344]
static constexpr size_t OFF_XB   = 5795840;      // bf16 [8192][672]
static constexpr size_t OFF_ZX   = 16805888;     // bf16 [8192][2968] (48.6MB)
static constexpr size_t OFF_DTRAW= 65433600;     // f32  [8192][24] raw dt accums
static constexpr size_t OFF_XIN  = 114061312;    // bf16 [8192][1344]
static constexpr size_t OFF_BM   = 136081408;    // bf16 [8192][128]
static constexpr size_t OFF_CM   = 138178560;    // bf16 [8192][128]
static constexpr size_t OFF_DTT  = 140275712;    // f32  [B][NH][L]
static constexpr size_t OFF_CDEC = 141062144;    // f32  [B][NH][NC]
static constexpr size_t OFF_G    = 141086720;    // f32  [B*NC][1024]
static constexpr size_t OFF_Y    = 142135296;    // bf16 [8192][1344]
static constexpr size_t OFF_Y2   = 164155392;    // bf16 [8192][1344]
static constexpr size_t OFF_ST   = 186175488;    // bf16 states: 44MB (2-pass) or 88MB (1-pass)
static constexpr size_t ST_ONEPASS_END = OFF_ST + (size_t)B_ * NH * NC * HD * DS * 2; // 274MB

__device__ __forceinline__ void gload16(const bf16* g, bf16* l) {
    __builtin_amdgcn_global_load_lds(
        (const __attribute__((address_space(1))) unsigned int*)g,
        (__attribute__((address_space(3))) unsigned int*)l, 16, 0, 0);
}
__device__ __forceinline__ float bf2f(short s) {
    unsigned int u = ((unsigned int)(unsigned short)s) << 16;
    return __builtin_bit_cast(float, u);
}
__device__ __forceinline__ short f2bf(float f) {
    bf16 h = __float2bfloat16(f);
    return *reinterpret_cast<short*>(&h);
}
__device__ __forceinline__ bf16 s2bf(short s) {
    unsigned short u = (unsigned short)s;
    return *reinterpret_cast<bf16*>(&u);
}

// ---------------- fused: input RMSNorm (blocks 0..NTOK) + weight cast (rest) ------
#define CASTBLK 2831
__global__ __launch_bounds__(256) void pre_kernel(
    const float* __restrict__ in, const float* __restrict__ w,
    bf16* __restrict__ out,
    const float* __restrict__ w1, const float* __restrict__ w2,
    bf16* __restrict__ w1b, bf16* __restrict__ w2b)
{
    const int tid = threadIdx.x;
    if (blockIdx.x < NTOK) {
        const int tok = blockIdx.x;
        __shared__ float red[4];
        float v[3];
        float ss = 0.f;
        int idx = tid;
#pragma unroll
        for (int j = 0; j < 3; ++j) {
            float x = 0.f;
            if (idx < DM) x = in[(size_t)tok * DM + idx];
            v[j] = x; ss += x * x;
            idx += 256;
        }
        for (int o = 32; o > 0; o >>= 1) ss += __shfl_down(ss, o, 64);
        if ((tid & 63) == 0) red[tid >> 6] = ss;
        __syncthreads();
        float tot = red[0] + red[1] + red[2] + red[3];
        float r = rsqrtf(tot / (float)DM + 1e-5f);
        idx = tid;
#pragma unroll
        for (int j = 0; j < 3; ++j) {
            if (idx < DM) out[(size_t)tok * DM + idx] = __float2bfloat16(v[j] * r * w[idx]);
            idx += 256;
        }
    } else {
        const int W1N = DIP * DM;
        const int W2N = DM * DI;
        int i = ((blockIdx.x - NTOK) * 256 + tid) * 4;
        if (i < W1N) {
            f32x4 v = *reinterpret_cast<const f32x4*>(w1 + i);
            s16x4 o;
#pragma unroll
            for (int j = 0; j < 4; ++j) o[j] = f2bf(v[j]);
            *reinterpret_cast<s16x4*>(w1b + i) = o;
        } else {
            int j4 = i - W1N;
            if (j4 < W2N) {
                f32x4 v = *reinterpret_cast<const f32x4*>(w2 + j4);
                s16x4 o;
#pragma unroll
                for (int j = 0; j < 4; ++j) o[j] = f2bf(v[j]);
                *reinterpret_cast<s16x4*>(w2b + j4) = o;
            }
        }
    }
}

// ---------------- GEMM1: 128x128, 4 waves, dbuf gload-lds, bf16 epilogue (R12-proven 59us)
__global__ __launch_bounds__(256) void gemm1_bf16(
    const bf16* __restrict__ A, const bf16* __restrict__ W,
    bf16* __restrict__ Co, float* __restrict__ dtraw,
    int M, int N, int K)
{
    __shared__ bf16 As[2 * 128 * 32];
    __shared__ bf16 Bs[2 * 128 * 32];
    const int tid = threadIdx.x, lane = tid & 63, w = tid >> 6;
    const int wm = w >> 1, wn = w & 1;
    const int m0 = blockIdx.x * 128, n0 = blockIdx.y * 128;
    const int lr = lane & 15, kg = lane >> 4;
    f32x4 acc[4][4] = {};

    const int sr = w * 32 + (lane >> 2);
    const int sc = (lane & 3) * 8;
    const bf16* ga0 = A + (size_t)(m0 + sr) * K + sc;
    const bf16* ga1 = ga0 + (size_t)16 * K;
    int nr0 = n0 + sr;      if (nr0 >= N) nr0 = N - 1;
    int nr1 = n0 + sr + 16; if (nr1 >= N) nr1 = N - 1;
    const bf16* gb0 = W + (size_t)nr0 * K + sc;
    const bf16* gb1 = W + (size_t)nr1 * K + sc;
    bf16* la = &As[w * 1024];
    bf16* lb = &Bs[w * 1024];

    const int nK = K >> 5;
    gload16(ga0, la); gload16(ga1, la + 512);
    gload16(gb0, lb); gload16(gb1, lb + 512);
    ga0 += 32; ga1 += 32; gb0 += 32; gb1 += 32;

    int cur = 0;
    for (int kt = 0; kt < nK; ++kt) {
        __syncthreads();
        if (kt + 1 < nK) {
            const int nb = (cur ^ 1) << 12;
            gload16(ga0, la + nb); gload16(ga1, la + nb + 512);
            gload16(gb0, lb + nb); gload16(gb1, lb + nb + 512);
            ga0 += 32; ga1 += 32; gb0 += 32; gb1 += 32;
        }
        const bf16* Ab = &As[cur << 12];
        const bf16* Bb = &Bs[cur << 12];
        short8 af[4], bfr[4];
#pragma unroll
        for (int i = 0; i < 4; ++i) {
            af[i]  = *reinterpret_cast<const short8*>(&Ab[(wm * 64 + i * 16 + lr) * 32 + kg * 8]);
            bfr[i] = *reinterpret_cast<const short8*>(&Bb[(wn * 64 + i * 16 + lr) * 32 + kg * 8]);
        }
#pragma unroll
        for (int i = 0; i < 4; ++i)
#pragma unroll
            for (int j = 0; j < 4; ++j)
                acc[i][j] = __builtin_amdgcn_mfma_f32_16x16x32_bf16(af[i], bfr[j], acc[i][j], 0, 0, 0);
        cur ^= 1;
    }
    // pure bf16 epilogue
#pragma unroll
    for (int i = 0; i < 4; ++i) {
        int row = m0 + wm * 64 + i * 16 + kg * 4;
#pragma unroll
        for (int j = 0; j < 4; ++j) {
            int col = n0 + wn * 64 + j * 16 + lr;
            if (col < N) {
#pragma unroll
                for (int r = 0; r < 4; ++r)
                    Co[(size_t)(row + r) * N + col] = __float2bfloat16(acc[i][j][r]);
            }
        }
    }
    // cold, block-uniform: raw f32 dt accums for cols [DI+CD, DI+CD+NH)
    if (blockIdx.y == (DI + CD) / 128) {
#pragma unroll
        for (int i = 0; i < 4; ++i) {
            int row = m0 + wm * 64 + i * 16 + kg * 4;
#pragma unroll
            for (int j = 0; j < 4; ++j) {
                int d = wn * 64 + j * 16 + lr;   // n0 == DI+CD exactly
                if (d < NH) {
#pragma unroll
                    for (int r = 0; r < 4; ++r)
                        dtraw[(size_t)(row + r) * NH + d] = acc[i][j][r];
                }
            }
        }
    }
}

// ---------------- GEMM2: 128x64 tile, 4 waves (32x64/wave), f32+resid out ----------
__global__ __launch_bounds__(256) void gemm2_bt(
    const bf16* __restrict__ A, const bf16* __restrict__ W,
    const float* __restrict__ resid, float* __restrict__ Co,
    int M, int N, int K)
{
    __shared__ bf16 As[2 * 128 * 32];   // buffer stride 4096 elems
    __shared__ bf16 Bs[2 * 64 * 32];    // buffer stride 2048 elems
    const int tid = threadIdx.x, lane = tid & 63, w = tid >> 6;  // w 0..3
    const int m0 = blockIdx.x * 128, n0 = blockIdx.y * 64;
    const int lr = lane & 15, kg = lane >> 4;
    f32x4 acc[2][4] = {};

    const int sr = lane >> 2;          // 0..15
    const int sc = (lane & 3) * 8;
    const bf16* ga0 = A + (size_t)(m0 + w * 32 + sr) * K + sc;
    const bf16* ga1 = ga0 + (size_t)16 * K;
    int nrB = n0 + w * 16 + sr; if (nrB >= N) nrB = N - 1;
    const bf16* gb0 = W + (size_t)nrB * K + sc;
    bf16* la = &As[w * 1024];   // + buf*4096
    bf16* lb = &Bs[w * 512];    // + buf*2048

    const int nK = K >> 5;   // 42
    gload16(ga0, la); gload16(ga1, la + 512); gload16(gb0, lb);
    ga0 += 32; ga1 += 32; gb0 += 32;

    int cur = 0;
    for (int kt = 0; kt < nK; ++kt) {
        __syncthreads();
        if (kt + 1 < nK) {
            const int nbA = (cur ^ 1) * 4096, nbB = (cur ^ 1) * 2048;
            gload16(ga0, la + nbA); gload16(ga1, la + nbA + 512);
            gload16(gb0, lb + nbB);
            ga0 += 32; ga1 += 32; gb0 += 32;
        }
        const bf16* Ab = &As[cur * 4096];
        const bf16* Bb = &Bs[cur * 2048];
        short8 af[2], bfr[4];
#pragma unroll
        for (int i = 0; i < 2; ++i)
            af[i] = *reinterpret_cast<const short8*>(&Ab[(w * 32 + i * 16 + lr) * 32 + kg * 8]);
#pragma unroll
        for (int j = 0; j < 4; ++j)
            bfr[j] = *reinterpret_cast<const short8*>(&Bb[(j * 16 + lr) * 32 + kg * 8]);
#pragma unroll
        for (int i = 0; i < 2; ++i)
#pragma unroll
            for (int j = 0; j < 4; ++j)
                acc[i][j] = __builtin_amdgcn_mfma_f32_16x16x32_bf16(af[i], bfr[j], acc[i][j], 0, 0, 0);
        cur ^= 1;
    }
#pragma unroll
    for (int i = 0; i < 2; ++i) {
        int row = m0 + w * 32 + i * 16 + kg * 4;
#pragma unroll
        for (int j = 0; j < 4; ++j) {
            int col = n0 + j * 16 + lr;
            if (col < N) {
#pragma unroll
                for (int r = 0; r < 4; ++r) {
                    size_t o = (size_t)(row + r) * N + col;
                    Co[o] = acc[i][j][r] + resid[o];
                }
            }
        }
    }
}

// ---------------- conv1d(4, causal, depthwise) + SiLU (bf16 in, x8) + dt ---------
__global__ __launch_bounds__(256) void conv_kernel(
    const bf16* __restrict__ zxb, const float* __restrict__ cw,
    const float* __restrict__ cb, const float* __restrict__ dtraw,
    const float* __restrict__ dtb,
    bf16* __restrict__ xin, bf16* __restrict__ Bm, bf16* __restrict__ Cm,
    float* __restrict__ dtT)      // [B][NH][L]
{
    const int tok = blockIdx.x;
    const int l = tok & (L_ - 1);
    const int tid = threadIdx.x;
    if (tid < 200) {
        const int ch0 = tid * 8;
        float xv[4][8];
#pragma unroll
        for (int k = 0; k < 4; ++k) {
            int li = l - 3 + k;
            if (li >= 0) {
                short8 v = *reinterpret_cast<const short8*>(
                    zxb + (size_t)(tok - 3 + k) * DIP + DI + ch0);
#pragma unroll
                for (int j = 0; j < 8; ++j) xv[k][j] = bf2f(v[j]);
            } else {
#pragma unroll
                for (int j = 0; j < 8; ++j) xv[k][j] = 0.f;
            }
        }
        const f32x4* cw4 = reinterpret_cast<const f32x4*>(cw + ch0 * 4);
        short8 o;
#pragma unroll
        for (int j = 0; j < 8; ++j) {
            f32x4 wv = cw4[j];
            float acc = cb[ch0 + j];
#pragma unroll
            for (int k = 0; k < 4; ++k) acc += xv[k][j] * wv[k];
            acc = acc / (1.f + expf(-acc));
            o[j] = f2bf(acc);
        }
        if (ch0 < DI)
            *reinterpret_cast<short8*>(xin + (size_t)tok * DI + ch0) = o;
        else if (ch0 < DI + DS)
            *reinterpret_cast<short8*>(Bm + (size_t)tok * DS + (ch0 - DI)) = o;
        else
            *reinterpret_cast<short8*>(Cm + (size_t)tok * DS + (ch0 - DI - DS)) = o;
    } else if (tid < 200 + NH) {
        const int hh = tid - 200;
        float v = dtraw[(size_t)tok * NH + hh] + dtb[hh];
        float sp = (v > 20.f) ? v : log1pf(expf(v));
        dtT[((size_t)((tok >> 11) * NH + hh)) * L_ + l] = sp;
    }
}

// ---------------- G = C.B^T per (b,chunk) via MFMA ----------------
__global__ __launch_bounds__(256) void g_mfma(
    const bf16* __restrict__ Bm, const bf16* __restrict__ Cm,
    float* __restrict__ Gp)
{
    const int bc = blockIdx.x;
    const int tok0 = (bc >> 6) * L_ + (bc & 63) * CH;
    const int tid = threadIdx.x, lane = tid & 63, w = tid >> 6;
    __shared__ bf16 Csh[32 * 136], Bsh[32 * 136];
    for (int g = tid; g < 512; g += 256) {
        int l = g >> 4, n0 = (g & 15) * 8;
        *reinterpret_cast<short8*>(&Csh[l * 136 + n0]) =
            *reinterpret_cast<const short8*>(Cm + (size_t)(tok0 + l) * DS + n0);
        *reinterpret_cast<short8*>(&Bsh[l * 136 + n0]) =
            *reinterpret_cast<const short8*>(Bm + (size_t)(tok0 + l) * DS + n0);
    }
    __syncthreads();
    const int mt = w >> 1, nt = w & 1;
    const int lr = lane & 15, kg = lane >> 4;
    f32x4 acc = {};
#pragma unroll
    for (int kt = 0; kt < 4; ++kt) {
        short8 a = *reinterpret_cast<const short8*>(&Csh[(mt * 16 + lr) * 136 + kt * 32 + kg * 8]);
        short8 b = *reinterpret_cast<const short8*>(&Bsh[(nt * 16 + lr) * 136 + kt * 32 + kg * 8]);
        acc = __builtin_amdgcn_mfma_f32_16x16x32_bf16(a, b, acc, 0, 0, 0);
    }
#pragma unroll
    for (int r = 0; r < 4; ++r) {
        int l = mt * 16 + kg * 4 + r, s = nt * 16 + lr;
        Gp[((size_t)bc << 10) + l * 32 + s] = acc[r];
    }
}

// ---------------- SSD phase B: per-chunk states via MFMA (vectorized staging) ------
__global__ __launch_bounds__(256) void ssd_states(
    const bf16* __restrict__ xin, const bf16* __restrict__ Bm,
    const float* __restrict__ dtT, const float* __restrict__ A_log,
    bf16* __restrict__ st, float* __restrict__ cdec, int nhp, int hs)
{
    const int blk = blockIdx.x;          // bh*NC + c
    const int c = blk & 63, bh = blk >> 6;
    const int hh = bh % nhp, b = bh / nhp;
    const int h = hs * nhp + hh;
    const int tok0 = b * L_ + c * CH;
    const int tid = threadIdx.x, lane = tid & 63, w = tid >> 6;
    const float Ah = -expf(A_log[h]);

    __shared__ bf16 xwT[64 * 40];    // A: [p][l] (x*wdec), rows >=56 zero
    __shared__ bf16 BmT[128 * 40];   // B: [n][l]
    __shared__ float dts[32], acum[32], wdec[32];

    if (tid < 32) dts[tid] = dtT[((size_t)(b * NH + h)) * L_ + c * CH + tid];
    __syncthreads();
    if (tid < 32) { float s = 0.f; for (int i = 0; i <= tid; ++i) s += dts[i]; acum[tid] = s * Ah; }
    __syncthreads();
    if (tid < 32) wdec[tid] = expf(acum[31] - acum[tid]) * dts[tid];
    if (tid == 0) cdec[(size_t)(b * NH + h) * NC + c] = expf(acum[31]);
    // BmT transpose-stage: vector global read (8 n), scalar LDS writes
    for (int g = tid; g < 512; g += 256) {
        int l = g >> 4, n0 = (g & 15) * 8;
        short8 v = *reinterpret_cast<const short8*>(Bm + (size_t)(tok0 + l) * DS + n0);
#pragma unroll
        for (int j = 0; j < 8; ++j) BmT[(n0 + j) * 40 + l] = s2bf(v[j]);
    }
    __syncthreads();                 // publishes wdec + BmT
    // xwT transpose-stage: vector global read (8 p), scaled scalar LDS writes
    if (tid < 256) {                 // 32 l x 8 p-groups
        int l = tid >> 3, p0 = (tid & 7) * 8;
        if (p0 < HD) {
            short8 v = *reinterpret_cast<const short8*>(
                xin + (size_t)(tok0 + l) * DI + h * HD + p0);
#pragma unroll
            for (int j = 0; j < 8; ++j)
                xwT[(p0 + j) * 40 + l] = __float2bfloat16(bf2f(v[j]) * wdec[l]);
        } else {
#pragma unroll
            for (int j = 0; j < 8; ++j)
                xwT[(p0 + j) * 40 + l] = __float2bfloat16(0.f);
        }
    }
    __syncthreads();

    const int lr = lane & 15, kg = lane >> 4;
    const int nt0 = w * 2;
    f32x4 acc[4][2] = {};
    short8 af[4], bfr[2];
#pragma unroll
    for (int mt = 0; mt < 4; ++mt)
        af[mt] = *reinterpret_cast<const short8*>(&xwT[(mt * 16 + lr) * 40 + kg * 8]);
#pragma unroll
    for (int j = 0; j < 2; ++j)
        bfr[j] = *reinterpret_cast<const short8*>(&BmT[((nt0 + j) * 16 + lr) * 40 + kg * 8]);
#pragma unroll
    for (int mt = 0; mt < 4; ++mt)
#pragma unroll
        for (int j = 0; j < 2; ++j)
            acc[mt][j] = __builtin_amdgcn_mfma_f32_16x16x32_bf16(af[mt], bfr[j], acc[mt][j], 0, 0, 0);

    bf16* sb = st + (size_t)blk * (HD * DS);
#pragma unroll
    for (int mt = 0; mt < 4; ++mt)
#pragma unroll
        for (int j = 0; j < 2; ++j) {
            int n = (nt0 + j) * 16 + lr;
#pragma unroll
            for (int r = 0; r < 4; ++r) {
                int p = mt * 16 + kg * 4 + r;
                if (p < HD) sb[p * DS + n] = __float2bfloat16(acc[mt][j][r]);
            }
        }
}

// ---------------- SSD phase C: in-place scan over chunks (R12-proven) ----------
__global__ __launch_bounds__(256) void ssd_scan(
    bf16* __restrict__ st, const float* __restrict__ cdec, int nhp, int hs)
{
    const int blk = blockIdx.x;   // bh*14 + sl
    const int sl = blk % 14;
    const int bh = blk / 14;
    const int b = bh / nhp, hh = bh % nhp;
    const int h = hs * nhp + hh;
    const int e = sl * 512 + threadIdx.x * 2;
    bf16* base = st + (size_t)bh * NC * (HD * DS) + e;
    const float* cd = cdec + (size_t)(b * NH + h) * NC;
    float c0 = 0.f, c1 = 0.f;
    for (int c = 0; c < NC; ++c) {
        unsigned int* p = reinterpret_cast<unsigned int*>(base + (size_t)c * (HD * DS));
        unsigned int sv = *p;
        float s0 = __builtin_bit_cast(float, sv << 16);
        float s1 = __builtin_bit_cast(float, sv & 0xffff0000u);
        bf16 h0 = __float2bfloat16(c0), h1 = __float2bfloat16(c1);
        unsigned int pvw = (unsigned int)*reinterpret_cast<unsigned short*>(&h0)
                         | ((unsigned int)*reinterpret_cast<unsigned short*>(&h1) << 16);
        *p = pvw;
        float d = cd[c];
        c0 = c0 * d + s0;
        c1 = c1 * d + s1;
    }
}

// ---------------- SSD phase D: Ydiag + Yoff + D*x via MFMA (prev direct-global) ----
__global__ __launch_bounds__(256) void ssd_out(
    const bf16* __restrict__ xin, const bf16* __restrict__ Cm,
    const float* __restrict__ dtT, const float* __restrict__ Gp,
    const bf16* __restrict__ prev, const float* __restrict__ A_log,
    const float* __restrict__ Dv, bf16* __restrict__ y, int nhp, int hs)
{
    const int blk = blockIdx.x;   // bh*NC + c
    const int c = blk & 63, bh = blk >> 6;
    const int hh = bh % nhp, b = bh / nhp;
    const int h = hs * nhp + hh;
    const int tok0 = b * L_ + c * CH;
    const int tid = threadIdx.x, lane = tid & 63, w = tid >> 6;
    const float Ah = -expf(A_log[h]);
    const float Dh = Dv[h];
    const int lr = lane & 15, kg = lane >> 4;
    const int p = w * 16 + lr;    // output headdim index (B-operand row)

    __shared__ bf16 Csh[32 * 136];
    __shared__ bf16 GtB[32 * 40];
    __shared__ bf16 xTB[64 * 40];
    __shared__ float dts[32], acum[32], ea[32];

    // direct global B-fragments of prev[p][n] (each element consumed once)
    const bf16* pv = prev + (size_t)blk * (HD * DS);
    short8 z8 = {0, 0, 0, 0, 0, 0, 0, 0};
    short8 bP[4] = {z8, z8, z8, z8};
    if (p < HD) {
#pragma unroll
        for (int kt = 0; kt < 4; ++kt)
            bP[kt] = *reinterpret_cast<const short8*>(pv + p * DS + kt * 32 + kg * 8);
    }

    if (tid < 32) dts[tid] = dtT[((size_t)(b * NH + h)) * L_ + c * CH + tid];
    __syncthreads();
    if (tid < 32) { float s = 0.f; for (int i = 0; i <= tid; ++i) s += dts[i]; acum[tid] = s * Ah; }
    __syncthreads();
    if (tid < 32) ea[tid] = expf(acum[tid]);
    // Csh stage: vector read + vector row-major LDS write (rows 272B, 16B-aligned)
    for (int g = tid; g < 512; g += 256) {
        int l = g >> 4, n0 = (g & 15) * 8;
        *reinterpret_cast<short8*>(&Csh[l * 136 + n0]) =
            *reinterpret_cast<const short8*>(Cm + (size_t)(tok0 + l) * DS + n0);
    }
    // xTB transpose-stage: vector global read (8 p), scalar LDS writes
    if (tid < 256) {                 // 32 s x 8 p-groups
        int s = tid >> 3, p0 = (tid & 7) * 8;
        if (p0 < HD) {
            short8 v = *reinterpret_cast<const short8*>(
                xin + (size_t)(tok0 + s) * DI + h * HD + p0);
#pragma unroll
            for (int j = 0; j < 8; ++j)
                xTB[(p0 + j) * 40 + s] = s2bf(v[j]);
        } else {
#pragma unroll
            for (int j = 0; j < 8; ++j)
                xTB[(p0 + j) * 40 + s] = __float2bfloat16(0.f);
        }
    }
    const float* grow = Gp + ((size_t)((b << 6) + c) << 10);
    for (int i = tid; i < 1024; i += 256) {
        int l = i >> 5, s = i & 31;
        float g = (s <= l) ? grow[i] * expf(acum[l] - acum[s]) * dts[s] : 0.f;
        GtB[l * 40 + s] = __float2bfloat16(g);
    }
    __syncthreads();

    short8 bX = *reinterpret_cast<const short8*>(&xTB[(w * 16 + lr) * 40 + kg * 8]);
    f32x4 accO[2] = {}, accD[2] = {};
#pragma unroll
    for (int mt = 0; mt < 2; ++mt) {
#pragma unroll
        for (int kt = 0; kt < 4; ++kt) {
            short8 a = *reinterpret_cast<const short8*>(&Csh[(mt * 16 + lr) * 136 + kt * 32 + kg * 8]);
            accO[mt] = __builtin_amdgcn_mfma_f32_16x16x32_bf16(a, bP[kt], accO[mt], 0, 0, 0);
        }
        short8 ag = *reinterpret_cast<const short8*>(&GtB[(mt * 16 + lr) * 40 + kg * 8]);
        accD[mt] = __builtin_amdgcn_mfma_f32_16x16x32_bf16(ag, bX, accD[mt], 0, 0, 0);
    }
    if (p < HD) {
#pragma unroll
        for (int mt = 0; mt < 2; ++mt)
#pragma unroll
            for (int r = 0; r < 4; ++r) {
                int l = mt * 16 + kg * 4 + r;
                float yv = ea[l] * accO[mt][r] + accD[mt][r]
                         + Dh * __bfloat162float(xTB[p * 40 + l]);
                y[(size_t)(tok0 + l) * DI + h * HD + p] = __float2bfloat16(yv);
            }
    }
}

// ---------------- gated RMSNorm (bf16 z, vectorized x8) ----------------
__global__ __launch_bounds__(256) void gated_norm_kernel(
    const bf16* __restrict__ yin, const bf16* __restrict__ zxb,
    const float* __restrict__ gw, bf16* __restrict__ y2)
{
    const int tok = blockIdx.x;
    const int tid = threadIdx.x;
    __shared__ float red[4];
    const int c0 = tid * 8;          // 168 active lanes cover DI=1344
    float v[8];
    float ss = 0.f;
    if (c0 < DI) {
        short8 yv = *reinterpret_cast<const short8*>(yin + (size_t)tok * DI + c0);
        short8 zv = *reinterpret_cast<const short8*>(zxb + (size_t)tok * DIP + c0);
#pragma unroll
        for (int j = 0; j < 8; ++j) {
            float y = bf2f(yv[j]);
            float z = bf2f(zv[j]);
            float val = y * (z / (1.f + expf(-z)));
            v[j] = val; ss += val * val;
        }
    }
    for (int o = 32; o > 0; o >>= 1) ss += __shfl_down(ss, o, 64);
    if ((tid & 63) == 0) red[tid >> 6] = ss;
    __syncthreads();
    float tot = red[0] + red[1] + red[2] + red[3];
    float r = rsqrtf(tot / (float)DI + 1e-5f);
    if (c0 < DI) {
        short8 o;
#pragma unroll
        for (int j = 0; j < 8; ++j) o[j] = f2bf(v[j] * r * gw[c0 + j]);
        *reinterpret_cast<short8*>(y2 + (size_t)tok * DI + c0) = o;
    }
}

// ---------------- launch ----------------
extern "C" void kernel_launch(void* const* d_in, const int* in_sizes, int n_in,
                              void* d_out, int out_size, void* d_ws, size_t ws_size,
                              hipStream_t stream)
{
    const float* hidden  = (const float*)d_in[0];
    const float* norm_w  = (const float*)d_in[1];
    const float* in_proj = (const float*)d_in[2];
    const float* conv_w  = (const float*)d_in[3];
    const float* conv_b  = (const float*)d_in[4];
    const float* dt_bias = (const float*)d_in[5];
    const float* A_log   = (const float*)d_in[6];
    const float* Dv      = (const float*)d_in[7];
    const float* gnw     = (const float*)d_in[8];
    const float* out_prj = (const float*)d_in[9];
    float* out = (float*)d_out;

    char* ws = (char*)d_ws;
    bf16*  w1b   = (bf16*)(ws + OFF_W1);
    bf16*  w2b   = (bf16*)(ws + OFF_W2);
    bf16*  xb    = (bf16*)(ws + OFF_XB);
    bf16*  zxb   = (bf16*)(ws + OFF_ZX);
    float* dtraw = (float*)(ws + OFF_DTRAW);
    bf16*  xin   = (bf16*)(ws + OFF_XIN);
    bf16*  Bm    = (bf16*)(ws + OFF_BM);
    bf16*  Cm    = (bf16*)(ws + OFF_CM);
    float* dtT   = (float*)(ws + OFF_DTT);
    float* cdec  = (float*)(ws + OFF_CDEC);
    float* Gp    = (float*)(ws + OFF_G);
    bf16*  yb    = (bf16*)(ws + OFF_Y);
    bf16*  y2    = (bf16*)(ws + OFF_Y2);
    bf16*  stb   = (bf16*)(ws + OFF_ST);

    const int npass = (ws_size >= ST_ONEPASS_END) ? 1 : 2;
    const int nhp = NH / npass;

    pre_kernel<<<NTOK + CASTBLK, 256, 0, stream>>>(hidden, norm_w, xb,
                                                   in_proj, out_prj, w1b, w2b);
    gemm1_bf16<<<dim3(NTOK / 128, (DIP + 127) / 128), 256, 0, stream>>>(
        xb, w1b, zxb, dtraw, NTOK, DIP, DM);
    conv_kernel<<<NTOK, 256, 0, stream>>>(zxb, conv_w, conv_b, dtraw, dt_bias,
                                          xin, Bm, Cm, dtT);
    g_mfma<<<B_ * NC, 256, 0, stream>>>(Bm, Cm, Gp);
    for (int hs = 0; hs < npass; ++hs) {
        ssd_states<<<B_ * nhp * NC, 256, 0, stream>>>(xin, Bm, dtT, A_log, stb, cdec, nhp, hs);
        ssd_scan<<<B_ * nhp * 14, 256, 0, stream>>>(stb, cdec, nhp, hs);
        ssd_out<<<B_ * nhp * NC, 256, 0, stream>>>(xin, Cm, dtT, Gp, stb, A_log, Dv, yb, nhp, hs);
    }
    gated_norm_kernel<<<NTOK, 256, 0, stream>>>(yb, zxb, gnw, y2);
    gemm2_bt<<<dim3(NTOK / 128, (DM + 63) / 64), 256, 0, stream>>>(
        y2, w2b, hidden, out, NTOK, DM, DI);
}